// Round 1
// baseline (423.996 us; speedup 1.0000x reference)
//
#include <hip/hip_runtime.h>

#define TPB 512

// Geometry (fixed by the problem): J=4, L=4, A=2, C_CH=1 -> 8 channels,
// B=4, M=N=128, P=640 pairs, 289 union shifts (|dx|,|dy| <= 8).
// corr[p,b,dx,dy] = sum_{u,v} a[u,v] * b[(u-dx)%128, (v-dy)%128]
// a = xpsi[j1,b,ch1], b = xpsi[j2,b,ch2]; output nonzero only for |dx|,|dy| <= r = 2^j2.

__global__ __launch_bounds__(TPB, 1)
void corr_kernel(const float* __restrict__ xpsi,
                 const int* __restrict__ la1,
                 const int* __restrict__ la2,
                 const int* __restrict__ shifted,
                 float* __restrict__ out)
{
    // pitches: 132/4=33 odd, 148/4=37 odd -> consecutive rows start in
    // different LDS bank-groups for float4 reads (conflict-minimal).
    __shared__ float a_lds[128 * 132];
    __shared__ float b_lds[128 * 148];

    const int bid   = blockIdx.x;
    const int pbo   = bid >> 8;        // / 256
    const int rest  = bid & 255;
    const int combo = rest >> 2;
    const int batch = rest & 3;
    // pair-blocks ordered j2-descending so heavy blocks dispatch first:
    // {3,6,8,9, 2,5,7, 1,4, 0} packed as nibbles (i0 = LSB nibble)
    const int pb = (int)((0x0417529863ULL >> (4 * pbo)) & 0xFULL);
    const int p  = pb * 64 + combo;

    const int j1  = la1[2 * p];
    const int ch1 = la1[2 * p + 1];
    const int j2  = la2[2 * p];
    const int ch2 = la2[2 * p + 1];
    const int r   = 1 << (shifted[p] - 1);   // = 2^j2

    const float* aimg = xpsi + (((size_t)j1 * 4 + batch) * 8 + ch1) * 16384;
    const float* bimg = xpsi + (((size_t)j2 * 4 + batch) * 8 + ch2) * 16384;

    const int tid = threadIdx.x;

    // stage a (plain, pitch 132)
    for (int i = tid; i < 16384; i += TPB)
        a_lds[(i >> 7) * 132 + (i & 127)] = aimg[i];
    // stage b with circular halo: b_lds[row][c] = bimg[row][(c-8) mod 128], c in [0,148)
    for (int i = tid; i < 128 * 148; i += TPB) {
        const int rr = i / 148;
        const int cc = i - rr * 148;
        b_lds[i] = bimg[(rr << 7) + ((cc + 120) & 127)];
    }
    __syncthreads();

    const int wave = tid >> 6;
    const int lane = tid & 63;

    // each wave handles one dx at a time
    for (int d = wave; d <= 2 * r; d += (TPB / 64)) {
        const int dx = d - r;

        float acc[17];
        #pragma unroll
        for (int i = 0; i < 17; ++i) acc[i] = 0.f;

        #pragma unroll
        for (int pass = 0; pass < 2; ++pass) {
            const int u  = lane + (pass << 6);
            const int up = (u - dx + 128) & 127;
            const float* arow = a_lds + u * 132;
            const float* brow = b_lds + up * 148;

            for (int v0 = 0; v0 < 128; v0 += 8) {
                float av[8];
                float w[24];
                const float4* ap = (const float4*)(arow + v0);
                const float4  A0 = ap[0], A1 = ap[1];
                av[0] = A0.x; av[1] = A0.y; av[2] = A0.z; av[3] = A0.w;
                av[4] = A1.x; av[5] = A1.y; av[6] = A1.z; av[7] = A1.w;
                const float4* bp = (const float4*)(brow + v0);
                #pragma unroll
                for (int k = 0; k < 6; ++k) {
                    const float4 W = bp[k];
                    w[4 * k]     = W.x; w[4 * k + 1] = W.y;
                    w[4 * k + 2] = W.z; w[4 * k + 3] = W.w;
                }
                // window index: b col (v0 + j - dy) -> w[j - dy + 8] (compile-time)
                #pragma unroll
                for (int dyi = 0; dyi < 17; ++dyi) {
                    const int dy = dyi - 8;
                    if (dy < -r || dy > r) continue;   // uniform runtime guard
                    #pragma unroll
                    for (int j = 0; j < 8; ++j)
                        acc[dyi] = fmaf(av[j], w[j - dy + 8], acc[dyi]);
                }
            }
        }

        // reduce across the 64 lanes (each lane summed different rows)
        #pragma unroll
        for (int dyi = 0; dyi < 17; ++dyi) {
            const int dy = dyi - 8;
            if (dy < -r || dy > r) continue;
            #pragma unroll
            for (int m = 1; m < 64; m <<= 1)
                acc[dyi] += __shfl_xor(acc[dyi], m, 64);
        }

        if (lane == 0) {
            const int xi = (dx >= 0) ? dx : dx + 17;
            float* op = out + (((size_t)p * 4 + batch) * 289) + xi * 17;
            #pragma unroll
            for (int dyi = 0; dyi < 17; ++dyi) {
                const int dy = dyi - 8;
                if (dy < -r || dy > r) continue;
                op[dy >= 0 ? dy : dy + 17] = acc[dyi];
            }
        }
    }
}

extern "C" void kernel_launch(void* const* d_in, const int* in_sizes, int n_in,
                              void* d_out, int out_size, void* d_ws, size_t ws_size,
                              hipStream_t stream) {
    const float* xpsi    = (const float*)d_in[0];
    // d_in[1] = masks_shift (unused: masks are exactly 1 on |dx|,|dy|<=r, else 0)
    const int*   la1     = (const int*)d_in[2];
    const int*   la2     = (const int*)d_in[3];
    const int*   shifted = (const int*)d_in[4];
    // d_in[5] = union_idx (layout derived analytically: xi*17+yi, S sorted)
    float* out = (float*)d_out;

    hipMemsetAsync(d_out, 0, (size_t)out_size * sizeof(float), stream);
    corr_kernel<<<2560, TPB, 0, stream>>>(xpsi, la1, la2, shifted, out);
}

// Round 2
// 224.957 us; speedup vs baseline: 1.8848x; 1.8848x over previous
//
#include <hip/hip_runtime.h>

typedef __attribute__((ext_vector_type(8))) short short8;
typedef __attribute__((ext_vector_type(4))) float float4v;

#define TPB 256

// 19 tiles: class j2=3: 9 n-tiles; j2=2: 5; j2=1: 3; j2=0: 2
__device__ __constant__ unsigned char TILE_J2[19] = {3,3,3,3,3,3,3,3,3, 2,2,2,2,2, 1,1,1, 0,0};
__device__ __constant__ unsigned char TILE_NT[19] = {0,1,2,3,4,5,6,7,8, 0,1,2,3,4, 0,1,2, 0,1};
__device__ __constant__ unsigned char PB_PREFIX[4] = {0,4,7,9};  // pair-block prefix per j1

static __device__ __forceinline__ unsigned short f2bf(float f) {
    unsigned int u = __builtin_bit_cast(unsigned int, f);
    u = (u + 0x7FFFu + ((u >> 16) & 1u)) >> 16;     // RNE, data has no NaN
    return (unsigned short)u;
}

// out[p][b][289] accumulated via atomicAdd over 8 K-chunks.
__global__ __launch_bounds__(TPB, 3)
void corr_mfma(const float* __restrict__ xpsi, float* __restrict__ out)
{
    // A: 32 m-rows x 520 px (512 + 8 pad; pitch 1040B, /16 = 65 odd)
    __shared__ __align__(16) unsigned short a_lds[32 * 520];
    // B: [nimg][rows][152 px] (144 + 8 pad; pitch 304B, /16 = 19 odd), max 6384 el
    __shared__ __align__(16) unsigned short b_lds[6400];

    const int bid = blockIdx.x;
    const int t   = bid % 19;
    const int rem = bid / 19;
    const int b   = rem & 3;
    const int kc  = rem >> 2;           // 0..7, K-rows [kc*16, kc*16+16)

    const int j2  = TILE_J2[t];
    const int r   = 1 << j2;
    const int dxN = 2 * r + 1;          // also dyN
    const int dyN = dxN;
    const int Mv  = 8 * (j2 + 1);       // valid m-rows
    const bool mf2 = (Mv > 16);
    const int n0  = TILE_NT[t] * 16;
    const int rows = 4 + 2 * r;         // B row-window per 4-row sub-chunk

    const int ch2lo = n0 / dxN;
    int nhi = n0 + 15; { int lim = 8 * dxN - 1; if (nhi > lim) nhi = lim; }
    const int ch2hi = nhi / dxN;
    const int nimg  = ch2hi - ch2lo + 1;

    const int tid  = threadIdx.x;
    const int lane = tid & 63;
    const int wv   = tid >> 6;
    const int c    = lane & 15;         // N-col in tile / A m-row
    const int g    = lane >> 4;         // K-group (8 px)

    const int ncol    = n0 + c;
    const bool validn = ncol < 8 * dxN;
    const int ncc     = validn ? ncol : n0;
    const int ch2     = ncc / dxN;
    const int dxi     = ncc - ch2 * dxN;
    const int ch2sel  = ch2 - ch2lo;
    const int dx      = dxi - r;
    const int xo      = dx < 0 ? dx + 17 : dx;
    const int bst     = (ch2sel * rows + (2 * r - dxi)) * 152;  // lane's B base (px)

    // how many dy this wave owns
    const int ndy = (dyN > wv) ? ((dyN - 1 - wv) >> 2) + 1 : 0;

    float4v acc0[5], acc1[5];
    #pragma unroll
    for (int i = 0; i < 5; ++i) { acc0[i] = (float4v)0.f; acc1[i] = (float4v)0.f; }

    for (int sub = 0; sub < 4; ++sub) {
        const int u0s = kc * 16 + sub * 4;

        // ---- stage A: 32 rows x 512 px (4 image rows), zero invalid rows ----
        for (int q = tid; q < 4096; q += TPB) {        // float4 granules
            const int m  = q >> 7;
            const int pq = q & 127;
            const int ur = pq >> 5;
            const int v  = (pq & 31) << 2;
            unsigned short o0 = 0, o1 = 0, o2 = 0, o3 = 0;
            if (m < Mv) {
                const int j1 = m >> 3, ch1 = m & 7;
                const float4 tv = *reinterpret_cast<const float4*>(
                    xpsi + (((size_t)j1 * 4 + b) * 8 + ch1) * 16384 + (u0s + ur) * 128 + v);
                o0 = f2bf(tv.x); o1 = f2bf(tv.y); o2 = f2bf(tv.z); o3 = f2bf(tv.w);
            }
            *reinterpret_cast<ushort4*>(&a_lds[m * 520 + (ur << 7) + v]) =
                ushort4{o0, o1, o2, o3};
        }
        // ---- stage B: nimg images, [rows][144] with dx-row + dy-col windows ----
        for (int ci = 0; ci < nimg; ++ci) {
            const float* img = xpsi + (((size_t)j2 * 4 + b) * 8 + ch2lo + ci) * 16384;
            const int tot = rows * 144;
            for (int i = tid; i < tot; i += TPB) {
                const int tr = i / 144;
                const int tc = i - tr * 144;
                const int sr = (u0s - r + tr) & 127;
                const int sc = (tc + r - 16) & 127;
                b_lds[(ci * rows + tr) * 152 + tc] = f2bf(img[sr * 128 + sc]);
            }
        }
        __syncthreads();

        if (ndy) {
            const unsigned short* ap = a_lds + c * 520;
            for (int ks = 0; ks < 16; ++ks) {
                const int koff = ks << 5;
                const int ul   = ks >> 2;
                const int vb   = (ks & 3) << 5;

                const short8 af0 = *(const short8*)(ap + koff + (g << 3));
                short8 af1 = af0;
                if (mf2) af1 = *(const short8*)(ap + 16 * 520 + koff + (g << 3));

                const unsigned short* bp = b_lds + bst + ul * 152 + vb + (g << 3);
                const uint4 wA = *(const uint4*)bp;
                const uint4 wB = *(const uint4*)(bp + 8);
                const uint4 wC = *(const uint4*)(bp + 16);
                const unsigned int wd[12] = {wA.x, wA.y, wA.z, wA.w,
                                             wB.x, wB.y, wB.z, wB.w,
                                             wC.x, wC.y, wC.z, wC.w};
                #pragma unroll
                for (int dyi = 0; dyi < 17; ++dyi) {
                    if ((dyi & 3) != wv) continue;
                    if (dyi >= dyN) continue;          // uniform
                    unsigned int o0, o1, o2, o3;
                    if ((dyi & 1) == 0) {
                        const int bb = 8 - (dyi >> 1);
                        o0 = wd[bb]; o1 = wd[bb + 1]; o2 = wd[bb + 2]; o3 = wd[bb + 3];
                    } else {
                        const int bb = (15 - dyi) >> 1;
                        o0 = (wd[bb]     >> 16) | (wd[bb + 1] << 16);
                        o1 = (wd[bb + 1] >> 16) | (wd[bb + 2] << 16);
                        o2 = (wd[bb + 2] >> 16) | (wd[bb + 3] << 16);
                        o3 = (wd[bb + 3] >> 16) | (wd[bb + 4] << 16);
                    }
                    union { unsigned int u[4]; short8 s; } bq;
                    bq.u[0] = o0; bq.u[1] = o1; bq.u[2] = o2; bq.u[3] = o3;
                    acc0[dyi >> 2] = __builtin_amdgcn_mfma_f32_16x16x32_bf16(
                        af0, bq.s, acc0[dyi >> 2], 0, 0, 0);
                    if (mf2)
                        acc1[dyi >> 2] = __builtin_amdgcn_mfma_f32_16x16x32_bf16(
                            af1, bq.s, acc1[dyi >> 2], 0, 0, 0);
                }
            }
        }
        __syncthreads();
    }

    // ---- store: atomicAdd partial sums ----
    if (!validn) return;
    #pragma unroll
    for (int dyi = 0; dyi < 17; ++dyi) {
        if ((dyi & 3) != wv) continue;
        if (dyi >= dyN) continue;
        const int dy = dyi - r;
        const int yo = dy < 0 ? dy + 17 : dy;
        #pragma unroll
        for (int f = 0; f < 2; ++f) {
            if (f && !mf2) continue;
            #pragma unroll
            for (int t2 = 0; t2 < 4; ++t2) {
                const int m = (g << 2) + t2 + (f << 4);
                if (m >= Mv) continue;
                const int j1 = m >> 3, ch1 = m & 7;
                const int pb = PB_PREFIX[j1] + (j2 - j1);
                const int p  = pb * 64 + ((ch1 >> 1) << 4) + ((ch2 >> 1) << 2)
                             + ((ch1 & 1) << 1) + (ch2 & 1);
                const float val = f ? acc1[dyi >> 2][t2] : acc0[dyi >> 2][t2];
                atomicAdd(out + (size_t)(p * 4 + b) * 289 + xo * 17 + yo, val);
            }
        }
    }
}

extern "C" void kernel_launch(void* const* d_in, const int* in_sizes, int n_in,
                              void* d_out, int out_size, void* d_ws, size_t ws_size,
                              hipStream_t stream) {
    const float* xpsi = (const float*)d_in[0];
    float* out = (float*)d_out;
    hipMemsetAsync(d_out, 0, (size_t)out_size * sizeof(float), stream);
    corr_mfma<<<19 * 4 * 8, TPB, 0, stream>>>(xpsi, out);
}

// Round 3
// 198.833 us; speedup vs baseline: 2.1324x; 1.1314x over previous
//
#include <hip/hip_runtime.h>

typedef __attribute__((ext_vector_type(8))) short short8;
typedef __attribute__((ext_vector_type(4))) float float4v;
typedef __attribute__((address_space(1))) const unsigned int gu32;
typedef __attribute__((address_space(3))) unsigned int lu32;

#define TPB 256
#define NXPSI (4*4*8*16384)      /* 2097152 fp32 elements */
#define NGR   (NXPSI/4)          /* 524288 float4 granules */
#define ZPG   64                 /* zero-page ushort4 granules -> 512B */

static __device__ __forceinline__ unsigned short f2bf(float f) {
    unsigned int u = __builtin_bit_cast(unsigned int, f);
    u = (u + 0x7FFFu + ((u >> 16) & 1u)) >> 16;     // RNE, data has no NaN
    return (unsigned short)u;
}

__global__ __launch_bounds__(256)
void conv_bf16(const float* __restrict__ in, unsigned short* __restrict__ outw) {
    const int g = blockIdx.x * 256 + threadIdx.x;
    if (g < NGR) {
        const float4 v = reinterpret_cast<const float4*>(in)[g];
        reinterpret_cast<ushort4*>(outw)[g] =
            ushort4{f2bf(v.x), f2bf(v.y), f2bf(v.z), f2bf(v.w)};
    } else if (g < NGR + ZPG) {
        reinterpret_cast<ushort4*>(outw)[g] = ushort4{0, 0, 0, 0};
    }
}

// corr[p,b,dx,dy] = sum_{u,v} a[u,v]*b[(u-dx)%128,(v-dy)%128]; nonzero |dx|,|dy|<=r=2^j2.
template<int J2, bool PRE>
static __device__ __forceinline__ void corr_body(
        const float* __restrict__ xpsi, const unsigned short* __restrict__ xbf,
        float* __restrict__ out, unsigned char* smem, int nt, int b, int kc)
{
    constexpr int R    = 1 << J2;
    constexpr int DXN  = 2 * R + 1;
    constexpr int DYN  = DXN;
    constexpr int MV   = 8 * (J2 + 1);
    constexpr int MR   = (J2 >= 2) ? 32 : 16;     // staged rows (zero-padded)
    constexpr int F    = (J2 >= 2) ? 2 : 1;       // M fragments
    constexpr int ROWS = 16 + 2 * R;              // B row window (16 K-rows + halo)
    constexpr int ABUF = MR * 256;                // elements per A buffer (2 K-rows)
    constexpr int NW   = (DYN + 3) >> 2;          // acc slots per wave

    unsigned short* a_lds = (unsigned short*)smem;                 // 2 x ABUF
    unsigned short* b_lds = (unsigned short*)(smem + 4 * ABUF);    // bytes

    const int n0 = nt * 16;
    const int k0 = kc * 16;

    const int ch2lo = n0 / DXN;
    int nhi = n0 + 15; if (nhi > 8 * DXN - 1) nhi = 8 * DXN - 1;
    const int nimg = nhi / DXN - ch2lo + 1;

    const int tid  = threadIdx.x;
    const int lane = tid & 63;
    const int wv   = tid >> 6;
    const int c    = lane & 15;       // N-col in tile / A m-row
    const int g    = lane >> 4;       // K-group

    const int ncol    = n0 + c;
    const bool validn = ncol < 8 * DXN;
    const int ncc     = validn ? ncol : n0;
    const int ch2     = ncc / DXN;
    const int dxi     = ncc - ch2 * DXN;
    const int dx      = dxi - R;
    const int xo      = dx < 0 ? dx + 17 : dx;
    const int bst     = ((ch2 - ch2lo) * ROWS + (2 * R - dxi)) * 152;

    // ---- stage B once: [nimg][ROWS][144+8pad], col tc <-> src (tc+R-16)&127 ----
    {
        const int tot = nimg * ROWS * 144;
        for (int i = tid; i < tot; i += TPB) {
            const int ci = i / (ROWS * 144);
            const int rr = i - ci * (ROWS * 144);
            const int tr = rr / 144;
            const int tc = rr - tr * 144;
            const int sr = (k0 - R + tr) & 127;
            const int sc = (tc + R - 16) & 127;
            b_lds[(ci * ROWS + tr) * 152 + tc] =
                f2bf(xpsi[((((size_t)J2 * 4 + b) * 8) + ch2lo + ci) * 16384 + sr * 128 + sc]);
        }
    }

    // ---- A stage: [m][2 K-rows x 128px] linear, 16B-granule XOR-swizzle (o^=m&7) ----
    auto stageA = [&](int sub, int bufi) {
        unsigned short* ab = a_lds + bufi * ABUF;
        constexpr int ng = MR * 32;               // 16B granules
        #pragma unroll
        for (int it = 0; it < ng / TPB; ++it) {
            const int o  = it * TPB + tid;
            const int m  = o >> 5;
            const int lo = (o & 31) ^ (m & 7);    // swizzle bits 0-2 of 16B index
            if (PRE) {
                const unsigned short* src;
                if (m < MV) {
                    const int j1 = m >> 3, ch1 = m & 7;
                    src = xbf + ((((size_t)j1 * 4 + b) * 8) + ch1) * 16384
                        + (k0 + sub * 2 + (lo >> 4)) * 128 + ((lo & 15) << 3);
                } else {
                    src = xbf + NXPSI + (lo << 3);            // zero page
                }
                __builtin_amdgcn_global_load_lds((gu32*)src, (lu32*)(ab + o * 8), 16, 0, 0);
            } else {
                ushort4 w0{0,0,0,0}, w1{0,0,0,0};
                if (m < MV) {
                    const int j1 = m >> 3, ch1 = m & 7;
                    const float* s = xpsi + ((((size_t)j1 * 4 + b) * 8) + ch1) * 16384
                                   + (k0 + sub * 2 + (lo >> 4)) * 128 + ((lo & 15) << 3);
                    const float4 f0 = ((const float4*)s)[0];
                    const float4 f1 = ((const float4*)s)[1];
                    w0 = ushort4{f2bf(f0.x), f2bf(f0.y), f2bf(f0.z), f2bf(f0.w)};
                    w1 = ushort4{f2bf(f1.x), f2bf(f1.y), f2bf(f1.z), f2bf(f1.w)};
                }
                *(ushort4*)(ab + o * 8)     = w0;
                *(ushort4*)(ab + o * 8 + 4) = w1;
            }
        }
    };

    float4v acc0[NW], acc1[NW];
    #pragma unroll
    for (int i = 0; i < NW; ++i) { acc0[i] = (float4v)0.f; acc1[i] = (float4v)0.f; }

    auto compute = [&](int sub, int bufi) {
        const char* abase = (const char*)(a_lds + bufi * ABUF);
        #pragma unroll
        for (int ks = 0; ks < 8; ++ks) {
            const int loff = ((((ks >> 2) << 8) | ((ks & 3) << 6) | (g << 4)) ^ ((c & 7) << 4));
            const short8 af0 = *(const short8*)(abase + c * 512 + loff);
            short8 af1 = af0;
            if (F == 2) af1 = *(const short8*)(abase + (c + 16) * 512 + loff);

            const unsigned short* bp = b_lds + bst + (sub * 2 + (ks >> 2)) * 152
                                     + ((ks & 3) << 5) + (g << 3);
            const uint4 wA = *(const uint4*)bp;
            const uint4 wB = *(const uint4*)(bp + 8);
            const uint4 wC = *(const uint4*)(bp + 16);
            const unsigned int wd[12] = {wA.x,wA.y,wA.z,wA.w, wB.x,wB.y,wB.z,wB.w,
                                         wC.x,wC.y,wC.z,wC.w};
            #pragma unroll
            for (int dyi = 0; dyi < DYN; ++dyi) {
                if ((dyi & 3) != wv) continue;            // wave owns dy % 4
                unsigned int o0, o1, o2, o3;
                if ((dyi & 1) == 0) {
                    const int bb = 8 - (dyi >> 1);
                    o0 = wd[bb]; o1 = wd[bb+1]; o2 = wd[bb+2]; o3 = wd[bb+3];
                } else {
                    const int bb = (15 - dyi) >> 1;        // v_alignbit pattern
                    o0 = (wd[bb]   >> 16) | (wd[bb+1] << 16);
                    o1 = (wd[bb+1] >> 16) | (wd[bb+2] << 16);
                    o2 = (wd[bb+2] >> 16) | (wd[bb+3] << 16);
                    o3 = (wd[bb+3] >> 16) | (wd[bb+4] << 16);
                }
                union { unsigned int u[4]; short8 s; } bq;
                bq.u[0] = o0; bq.u[1] = o1; bq.u[2] = o2; bq.u[3] = o3;
                acc0[dyi >> 2] = __builtin_amdgcn_mfma_f32_16x16x32_bf16(
                    af0, bq.s, acc0[dyi >> 2], 0, 0, 0);
                if (F == 2)
                    acc1[dyi >> 2] = __builtin_amdgcn_mfma_f32_16x16x32_bf16(
                        af1, bq.s, acc1[dyi >> 2], 0, 0, 0);
            }
        }
    };

    stageA(0, 0);
    __syncthreads();
    for (int sub = 0; sub < 8; ++sub) {
        if (sub < 7) stageA(sub + 1, (sub + 1) & 1);   // async prefetch under compute
        compute(sub, sub & 1);
        __syncthreads();                                // drains vmcnt + lgkm
    }

    if (!validn) return;
    #pragma unroll
    for (int dyi = 0; dyi < DYN; ++dyi) {
        if ((dyi & 3) != wv) continue;
        const int dy = dyi - R;
        const int yo = dy < 0 ? dy + 17 : dy;
        #pragma unroll
        for (int f = 0; f < F; ++f) {
            #pragma unroll
            for (int t2 = 0; t2 < 4; ++t2) {
                const int m = (g << 2) + t2 + (f << 4);
                if (m >= MV) continue;
                const int j1 = m >> 3, ch1 = m & 7;
                const int pb = ((j1 * (9 - j1)) >> 1) + (J2 - j1);
                const int p  = pb * 64 + ((ch1 >> 1) << 4) + ((ch2 >> 1) << 2)
                             + ((ch1 & 1) << 1) + (ch2 & 1);
                const float val = f ? acc1[dyi >> 2][t2] : acc0[dyi >> 2][t2];
                atomicAdd(out + (size_t)(p * 4 + b) * 289 + xo * 17 + yo, val);
            }
        }
    }
}

template<bool PRE>
__global__ __launch_bounds__(TPB, 3)
void corr_v3(const float* __restrict__ xpsi, const unsigned short* __restrict__ xbf,
             float* __restrict__ out)
{
    __shared__ __align__(16) unsigned char smem[53248];
    const int bid = blockIdx.x;
    const int t   = bid % 19;          // tiles j2-descending -> heavy blocks first
    const int rem = bid / 19;
    const int b   = rem & 3;
    const int kc  = rem >> 2;
    if (t < 9)       corr_body<3, PRE>(xpsi, xbf, out, smem, t,      b, kc);
    else if (t < 14) corr_body<2, PRE>(xpsi, xbf, out, smem, t - 9,  b, kc);
    else if (t < 17) corr_body<1, PRE>(xpsi, xbf, out, smem, t - 14, b, kc);
    else             corr_body<0, PRE>(xpsi, xbf, out, smem, t - 17, b, kc);
}

extern "C" void kernel_launch(void* const* d_in, const int* in_sizes, int n_in,
                              void* d_out, int out_size, void* d_ws, size_t ws_size,
                              hipStream_t stream) {
    const float* xpsi = (const float*)d_in[0];
    float* out = (float*)d_out;
    hipMemsetAsync(d_out, 0, (size_t)out_size * sizeof(float), stream);
    if (ws_size >= (size_t)(NXPSI * 2 + ZPG * 8)) {
        unsigned short* xbf = (unsigned short*)d_ws;
        conv_bf16<<<(NGR + ZPG + 255) / 256, 256, 0, stream>>>(xpsi, xbf);
        corr_v3<true><<<608, TPB, 0, stream>>>(xpsi, xbf, out);
    } else {
        corr_v3<false><<<608, TPB, 0, stream>>>(xpsi, nullptr, out);
    }
}

// Round 4
// 60.586 us; speedup vs baseline: 6.9983x; 3.2819x over previous
//
#include <hip/hip_runtime.h>

typedef __attribute__((ext_vector_type(8))) short short8;
typedef __attribute__((ext_vector_type(4))) float float4v;
typedef __attribute__((address_space(1))) const unsigned int gu32;
typedef __attribute__((address_space(3))) unsigned int lu32;

#define TPB 256
#define NXPSI (4*4*8*16384)      /* 2097152 fp32 elements */
#define NGR   (NXPSI/4)          /* 524288 float4 granules */
#define ZPG   64                 /* zero-page ushort4 granules -> 512B */
#define PBYTE (NXPSI*2 + ZPG*8)  /* partial region byte offset = 4194816 */
#define NPART 3207168            /* partial floats total */
#define NOUT  739840             /* 640*4*289 */

// partial float-offset base per global tile t (19 tiles: 9xJ2=3, 5xJ2=2, 3xJ2=1, 2xJ2=0)
__device__ __constant__ int TBASE[19] = {
    0, 278528, 557056, 835584, 1114112, 1392640, 1671168, 1949696, 2228224,
    2506752, 2617344, 2727936, 2838528, 2949120,
    3059712, 3100672, 3141632,
    3182592, 3194880};
__device__ __constant__ unsigned char J1T[10] = {0,0,0,0,1,1,1,2,2,3};
__device__ __constant__ unsigned char J2T[10] = {0,1,2,3,1,2,3,2,3,3};
__device__ __constant__ unsigned char TSTART[4] = {17,14,9,0};   // class->first tile

static __device__ __forceinline__ unsigned short f2bf(float f) {
    unsigned int u = __builtin_bit_cast(unsigned int, f);
    u = (u + 0x7FFFu + ((u >> 16) & 1u)) >> 16;     // RNE, data has no NaN
    return (unsigned short)u;
}

__global__ __launch_bounds__(256)
void conv_bf16(const float* __restrict__ in, unsigned short* __restrict__ outw) {
    const int g = blockIdx.x * 256 + threadIdx.x;
    if (g < NGR) {
        const float4 v = reinterpret_cast<const float4*>(in)[g];
        reinterpret_cast<ushort4*>(outw)[g] =
            ushort4{f2bf(v.x), f2bf(v.y), f2bf(v.z), f2bf(v.w)};
    } else if (g < NGR + ZPG) {
        reinterpret_cast<ushort4*>(outw)[g] = ushort4{0, 0, 0, 0};
    }
}

// corr[p,b,dx,dy] = sum_{u,v} a[u,v]*b[(u-dx)%128,(v-dy)%128]; nonzero |dx|,|dy|<=r=2^j2.
template<int J2, bool PRE, bool PART>
static __device__ __forceinline__ void corr_body(
        const float* __restrict__ xpsi, const unsigned short* __restrict__ xbf,
        float* __restrict__ out, float* __restrict__ part,
        unsigned char* smem, int tglob, int nt, int b, int kc)
{
    constexpr int R    = 1 << J2;
    constexpr int DXN  = 2 * R + 1;
    constexpr int DYN  = DXN;
    constexpr int MV   = 8 * (J2 + 1);
    constexpr int MR   = (J2 >= 2) ? 32 : 16;     // staged rows (zero-padded)
    constexpr int F    = (J2 >= 2) ? 2 : 1;       // M fragments
    constexpr int ROWS = 16 + 2 * R;              // B row window (16 K-rows + halo)
    constexpr int ABUF = MR * 256;                // elements per A buffer (2 K-rows)
    constexpr int NW   = (DYN + 3) >> 2;          // acc slots per wave

    unsigned short* a_lds = (unsigned short*)smem;                 // 2 x ABUF
    unsigned short* b_lds = (unsigned short*)(smem + 4 * ABUF);    // bytes

    const int n0 = nt * 16;
    const int k0 = kc * 16;

    const int ch2lo = n0 / DXN;
    int nhi = n0 + 15; if (nhi > 8 * DXN - 1) nhi = 8 * DXN - 1;
    const int nimg = nhi / DXN - ch2lo + 1;

    const int tid  = threadIdx.x;
    const int lane = tid & 63;
    const int wv   = tid >> 6;
    const int c    = lane & 15;       // N-col in tile / A m-row
    const int g    = lane >> 4;       // K-group

    const int ncol    = n0 + c;
    const bool validn = ncol < 8 * DXN;
    const int ncc     = validn ? ncol : n0;
    const int ch2     = ncc / DXN;
    const int dxi     = ncc - ch2 * DXN;
    const int dx      = dxi - R;
    const int xo      = dx < 0 ? dx + 17 : dx;
    const int bst     = ((ch2 - ch2lo) * ROWS + (2 * R - dxi)) * 152;

    // ---- stage B once: [nimg][ROWS][144+8pad], col tc <-> src (tc+R-16)&127 ----
    {
        const int tot = nimg * ROWS * 144;
        for (int i = tid; i < tot; i += TPB) {
            const int ci = i / (ROWS * 144);
            const int rr = i - ci * (ROWS * 144);
            const int tr = rr / 144;
            const int tc = rr - tr * 144;
            const int sr = (k0 - R + tr) & 127;
            const int sc = (tc + R - 16) & 127;
            b_lds[(ci * ROWS + tr) * 152 + tc] =
                f2bf(xpsi[((((size_t)J2 * 4 + b) * 8) + ch2lo + ci) * 16384 + sr * 128 + sc]);
        }
    }

    // ---- A stage: [m][2 K-rows x 128px] linear, 16B-granule XOR-swizzle (o^=m&7) ----
    auto stageA = [&](int sub, int bufi) {
        unsigned short* ab = a_lds + bufi * ABUF;
        constexpr int ng = MR * 32;               // 16B granules
        #pragma unroll
        for (int it = 0; it < ng / TPB; ++it) {
            const int o  = it * TPB + tid;
            const int m  = o >> 5;
            const int lo = (o & 31) ^ (m & 7);    // swizzle bits 0-2 of 16B index
            if (PRE) {
                const unsigned short* src;
                if (m < MV) {
                    const int j1 = m >> 3, ch1 = m & 7;
                    src = xbf + ((((size_t)j1 * 4 + b) * 8) + ch1) * 16384
                        + (k0 + sub * 2 + (lo >> 4)) * 128 + ((lo & 15) << 3);
                } else {
                    src = xbf + NXPSI + (lo << 3);            // zero page
                }
                __builtin_amdgcn_global_load_lds((gu32*)src, (lu32*)(ab + o * 8), 16, 0, 0);
            } else {
                ushort4 w0{0,0,0,0}, w1{0,0,0,0};
                if (m < MV) {
                    const int j1 = m >> 3, ch1 = m & 7;
                    const float* s = xpsi + ((((size_t)j1 * 4 + b) * 8) + ch1) * 16384
                                   + (k0 + sub * 2 + (lo >> 4)) * 128 + ((lo & 15) << 3);
                    const float4 f0 = ((const float4*)s)[0];
                    const float4 f1 = ((const float4*)s)[1];
                    w0 = ushort4{f2bf(f0.x), f2bf(f0.y), f2bf(f0.z), f2bf(f0.w)};
                    w1 = ushort4{f2bf(f1.x), f2bf(f1.y), f2bf(f1.z), f2bf(f1.w)};
                }
                *(ushort4*)(ab + o * 8)     = w0;
                *(ushort4*)(ab + o * 8 + 4) = w1;
            }
        }
    };

    float4v acc0[NW], acc1[NW];
    #pragma unroll
    for (int i = 0; i < NW; ++i) { acc0[i] = (float4v)0.f; acc1[i] = (float4v)0.f; }

    auto compute = [&](int sub, int bufi) {
        const char* abase = (const char*)(a_lds + bufi * ABUF);
        #pragma unroll
        for (int ks = 0; ks < 8; ++ks) {
            const int loff = ((((ks >> 2) << 8) | ((ks & 3) << 6) | (g << 4)) ^ ((c & 7) << 4));
            const short8 af0 = *(const short8*)(abase + c * 512 + loff);
            short8 af1 = af0;
            if (F == 2) af1 = *(const short8*)(abase + (c + 16) * 512 + loff);

            const unsigned short* bp = b_lds + bst + (sub * 2 + (ks >> 2)) * 152
                                     + ((ks & 3) << 5) + (g << 3);
            const uint4 wA = *(const uint4*)bp;
            const uint4 wB = *(const uint4*)(bp + 8);
            const uint4 wC = *(const uint4*)(bp + 16);
            const unsigned int wd[12] = {wA.x,wA.y,wA.z,wA.w, wB.x,wB.y,wB.z,wB.w,
                                         wC.x,wC.y,wC.z,wC.w};
            #pragma unroll
            for (int dyi = 0; dyi < DYN; ++dyi) {
                if ((dyi & 3) != wv) continue;            // wave owns dy % 4
                unsigned int o0, o1, o2, o3;
                if ((dyi & 1) == 0) {
                    const int bb = 8 - (dyi >> 1);
                    o0 = wd[bb]; o1 = wd[bb+1]; o2 = wd[bb+2]; o3 = wd[bb+3];
                } else {
                    const int bb = (15 - dyi) >> 1;        // v_alignbit pattern
                    o0 = (wd[bb]   >> 16) | (wd[bb+1] << 16);
                    o1 = (wd[bb+1] >> 16) | (wd[bb+2] << 16);
                    o2 = (wd[bb+2] >> 16) | (wd[bb+3] << 16);
                    o3 = (wd[bb+3] >> 16) | (wd[bb+4] << 16);
                }
                union { unsigned int u[4]; short8 s; } bq;
                bq.u[0] = o0; bq.u[1] = o1; bq.u[2] = o2; bq.u[3] = o3;
                acc0[dyi >> 2] = __builtin_amdgcn_mfma_f32_16x16x32_bf16(
                    af0, bq.s, acc0[dyi >> 2], 0, 0, 0);
                if (F == 2)
                    acc1[dyi >> 2] = __builtin_amdgcn_mfma_f32_16x16x32_bf16(
                        af1, bq.s, acc1[dyi >> 2], 0, 0, 0);
            }
        }
    };

    stageA(0, 0);
    __syncthreads();
    for (int sub = 0; sub < 8; ++sub) {
        if (sub < 7) stageA(sub + 1, (sub + 1) & 1);   // async prefetch under compute
        compute(sub, sub & 1);
        __syncthreads();                                // drains vmcnt + lgkm
    }

    if (!validn) return;

    if (PART) {
        // plain stores: partial[t][kc][b][dyi][m][c] (c contiguous -> 64B/16 lanes)
        float* pt = part + TBASE[tglob] + (size_t)(kc * 4 + b) * DYN * MV * 16;
        #pragma unroll
        for (int dyi = 0; dyi < DYN; ++dyi) {
            if ((dyi & 3) != wv) continue;
            #pragma unroll
            for (int f = 0; f < F; ++f) {
                #pragma unroll
                for (int t2 = 0; t2 < 4; ++t2) {
                    const int m = (g << 2) + t2 + (f << 4);
                    if (m >= MV) continue;
                    const float val = f ? acc1[dyi >> 2][t2] : acc0[dyi >> 2][t2];
                    pt[(dyi * MV + m) * 16 + c] = val;
                }
            }
        }
    } else {
        #pragma unroll
        for (int dyi = 0; dyi < DYN; ++dyi) {
            if ((dyi & 3) != wv) continue;
            const int dy = dyi - R;
            const int yo = dy < 0 ? dy + 17 : dy;
            #pragma unroll
            for (int f = 0; f < F; ++f) {
                #pragma unroll
                for (int t2 = 0; t2 < 4; ++t2) {
                    const int m = (g << 2) + t2 + (f << 4);
                    if (m >= MV) continue;
                    const int j1 = m >> 3, ch1 = m & 7;
                    const int pb = ((j1 * (9 - j1)) >> 1) + (J2 - j1);
                    const int p  = pb * 64 + ((ch1 >> 1) << 4) + ((ch2 >> 1) << 2)
                                 + ((ch1 & 1) << 1) + (ch2 & 1);
                    const float val = f ? acc1[dyi >> 2][t2] : acc0[dyi >> 2][t2];
                    atomicAdd(out + (size_t)(p * 4 + b) * 289 + xo * 17 + yo, val);
                }
            }
        }
    }
}

template<bool PRE, bool PART>
__global__ __launch_bounds__(TPB, 3)
void corr_v3(const float* __restrict__ xpsi, const unsigned short* __restrict__ xbf,
             float* __restrict__ out, float* __restrict__ part)
{
    __shared__ __align__(16) unsigned char smem[53248];
    const int bid = blockIdx.x;
    const int t   = bid % 19;
    const int rem = bid / 19;
    const int b   = rem & 3;
    const int kc  = rem >> 2;
    if (t < 9)       corr_body<3, PRE, PART>(xpsi, xbf, out, part, smem, t, t,      b, kc);
    else if (t < 14) corr_body<2, PRE, PART>(xpsi, xbf, out, part, smem, t, t - 9,  b, kc);
    else if (t < 17) corr_body<1, PRE, PART>(xpsi, xbf, out, part, smem, t, t - 14, b, kc);
    else             corr_body<0, PRE, PART>(xpsi, xbf, out, part, smem, t, t - 17, b, kc);
}

// sum 8 kc-partials -> out[p][b][289]; writes masked zeros too (no memset needed)
__global__ __launch_bounds__(256)
void reduce_k(const float* __restrict__ part, float* __restrict__ out)
{
    const int o = blockIdx.x * 256 + threadIdx.x;
    if (o >= NOUT) return;
    const int p  = o / 1156;            // 4*289
    const int r1 = o - p * 1156;
    const int b  = r1 / 289;
    const int s  = r1 - b * 289;
    const int xo = s / 17, yo = s - xo * 17;
    const int pb = p >> 6, cc = p & 63;
    const int j1 = J1T[pb], j2 = J2T[pb];
    const int R  = 1 << j2;
    const int dx = xo <= 8 ? xo : xo - 17;
    const int dy = yo <= 8 ? yo : yo - 17;
    float v = 0.f;
    if (dx >= -R && dx <= R && dy >= -R && dy <= R) {
        const int ch1 = ((cc >> 4) & 3) * 2 + ((cc >> 1) & 1);
        const int ch2 = ((cc >> 2) & 3) * 2 + (cc & 1);
        const int DYN = 2 * R + 1, MV = 8 * (j2 + 1);
        const int ncol = ch2 * DYN + (dx + R);
        const int t = TSTART[j2] + (ncol >> 4);
        const int c = ncol & 15;
        const int m = j1 * 8 + ch1;
        const float* q = part + TBASE[t]
                       + ((size_t)(b * DYN + (dy + R)) * MV + m) * 16 + c;
        const int kstr = 4 * DYN * MV * 16;
        #pragma unroll
        for (int kc = 0; kc < 8; ++kc) v += q[(size_t)kc * kstr];
    }
    out[o] = v;
}

extern "C" void kernel_launch(void* const* d_in, const int* in_sizes, int n_in,
                              void* d_out, int out_size, void* d_ws, size_t ws_size,
                              hipStream_t stream) {
    const float* xpsi = (const float*)d_in[0];
    float* out = (float*)d_out;

    if (ws_size >= (size_t)PBYTE + (size_t)NPART * 4) {
        // full path: bf16 pre-convert + partial stores + reduction (no atomics)
        unsigned short* xbf = (unsigned short*)d_ws;
        float* part = (float*)((char*)d_ws + PBYTE);
        conv_bf16<<<(NGR + ZPG + 255) / 256, 256, 0, stream>>>(xpsi, xbf);
        corr_v3<true, true><<<608, TPB, 0, stream>>>(xpsi, xbf, out, part);
        reduce_k<<<(NOUT + 255) / 256, 256, 0, stream>>>(part, out);
    } else if (ws_size >= (size_t)PBYTE) {
        unsigned short* xbf = (unsigned short*)d_ws;
        hipMemsetAsync(d_out, 0, (size_t)out_size * sizeof(float), stream);
        conv_bf16<<<(NGR + ZPG + 255) / 256, 256, 0, stream>>>(xpsi, xbf);
        corr_v3<true, false><<<608, TPB, 0, stream>>>(xpsi, xbf, out, nullptr);
    } else {
        hipMemsetAsync(d_out, 0, (size_t)out_size * sizeof(float), stream);
        corr_v3<false, false><<<608, TPB, 0, stream>>>(xpsi, nullptr, out, nullptr);
    }
}

// Round 5
// 56.375 us; speedup vs baseline: 7.5210x; 1.0747x over previous
//
#include <hip/hip_runtime.h>

typedef __attribute__((ext_vector_type(8))) short short8;
typedef __attribute__((ext_vector_type(4))) float float4v;
typedef __attribute__((address_space(1))) const unsigned int gu32;
typedef __attribute__((address_space(3))) unsigned int lu32;

#define TPB 256
#define NXPSI (4*4*8*16384)      /* 2097152 fp32 elements */
#define NGR   (NXPSI/4)          /* 524288 float4 granules */
#define ZPG   64                 /* zero-page ushort4 granules (legacy, kept in layout) */
#define PBYTE (NXPSI*2 + ZPG*8)  /* partial region byte offset = 4194816 */
#define NPART 12828672           /* partial floats: 32 (kc,wv) slices */
#define NOUT  739840             /* 640*4*289 */

// per-tile partial base (floats). size(t) = 32*4*DYN*MV*16
__device__ __constant__ int TBASE[19] = {
    0, 1114112, 2228224, 3342336, 4456448, 5570560, 6684672, 7798784, 8912896,
    10027008, 10469376, 10911744, 11354112, 11796480,
    12238848, 12402688, 12566528,
    12730368, 12779520};

static __device__ __forceinline__ unsigned short f2bf(float f) {
    unsigned int u = __builtin_bit_cast(unsigned int, f);
    u = (u + 0x7FFFu + ((u >> 16) & 1u)) >> 16;     // RNE, data has no NaN
    return (unsigned short)u;
}

__global__ __launch_bounds__(256)
void conv_bf16(const float* __restrict__ in, unsigned short* __restrict__ outw) {
    const int g = blockIdx.x * 256 + threadIdx.x;
    if (g < NGR) {
        const float4 v = reinterpret_cast<const float4*>(in)[g];
        reinterpret_cast<ushort4*>(outw)[g] =
            ushort4{f2bf(v.x), f2bf(v.y), f2bf(v.z), f2bf(v.w)};
    } else if (g < NGR + ZPG) {
        reinterpret_cast<ushort4*>(outw)[g] = ushort4{0, 0, 0, 0};
    }
}

// corr[p,b,dx,dy] = sum_{u,v} a[u,v]*b[(u-dx)%128,(v-dy)%128]; nonzero |dx|,|dy|<=r=2^j2.
// Waves split K (wave wv owns ks = wv, wv+4); each wave computes ALL dyi.
template<int J2, bool PRE, bool PART>
static __device__ __forceinline__ void corr_body(
        const float* __restrict__ xpsi, const unsigned short* __restrict__ xbf,
        float* __restrict__ out, float* __restrict__ part,
        unsigned char* smem, int tglob, int nt, int b, int kc)
{
    constexpr int R    = 1 << J2;
    constexpr int DXN  = 2 * R + 1;
    constexpr int DYN  = DXN;
    constexpr int MV   = 8 * (J2 + 1);            // valid m-rows == staged rows
    constexpr int F    = (J2 >= 2) ? 2 : 1;       // M fragments
    constexpr int ROWS = 16 + 2 * R;              // B row window
    constexpr int ABUF = MV * 256;                // elements per A buffer (2 K-rows)
    constexpr int S    = DYN * MV * 16;           // floats per partial slice

    unsigned short* a_lds = (unsigned short*)smem;                  // 2 x ABUF
    unsigned short* b_lds = (unsigned short*)(smem + 4 * ABUF);

    const int n0 = nt * 16;
    const int k0 = kc * 16;

    const int ch2lo = n0 / DXN;
    int nhi = n0 + 15; if (nhi > 8 * DXN - 1) nhi = 8 * DXN - 1;
    const int nimg = nhi / DXN - ch2lo + 1;

    const int tid  = threadIdx.x;
    const int lane = tid & 63;
    const int wv   = tid >> 6;
    const int c    = lane & 15;       // N-col in tile / A m-row
    const int g    = lane >> 4;       // K-group

    const int ncol    = n0 + c;
    const bool validn = ncol < 8 * DXN;
    const int ncc     = validn ? ncol : n0;
    const int ch2     = ncc / DXN;
    const int dxi     = ncc - ch2 * DXN;
    const int dx      = dxi - R;
    const int xo      = dx < 0 ? dx + 17 : dx;
    const int bst     = ((ch2 - ch2lo) * ROWS + (2 * R - dxi)) * 152;

    // ---- stage B once: [nimg][ROWS][144 +8pad], col tc <-> src (tc+R-16)&127 ----
    if (PRE) {
        if (J2 >= 2) {
            // wrap boundary is 4-aligned for R in {4,8} -> clean ushort4 granules
            for (int ci = 0; ci < nimg; ++ci) {
                const unsigned short* img = xbf + ((((size_t)J2*4 + b)*8) + ch2lo + ci) * 16384;
                const int ng2 = ROWS * 36;
                for (int i = tid; i < ng2; i += TPB) {
                    const int tr = i / 36, tc = (i - tr * 36) * 4;
                    const int sr = (k0 - R + tr) & 127;
                    const int sc = (tc + R - 16) & 127;
                    *(ushort4*)(b_lds + (ci * ROWS + tr) * 152 + tc) =
                        *(const ushort4*)(img + sr * 128 + sc);
                }
            }
        } else {
            const int tot = nimg * ROWS * 144;
            for (int i = tid; i < tot; i += TPB) {
                const int ci = i / (ROWS * 144);
                const int rr = i - ci * (ROWS * 144);
                const int tr = rr / 144, tc = rr - tr * 144;
                const int sr = (k0 - R + tr) & 127;
                const int sc = (tc + R - 16) & 127;
                b_lds[(ci * ROWS + tr) * 152 + tc] =
                    xbf[((((size_t)J2*4 + b)*8) + ch2lo + ci) * 16384 + sr * 128 + sc];
            }
        }
    } else {
        const int tot = nimg * ROWS * 144;
        for (int i = tid; i < tot; i += TPB) {
            const int ci = i / (ROWS * 144);
            const int rr = i - ci * (ROWS * 144);
            const int tr = rr / 144, tc = rr - tr * 144;
            const int sr = (k0 - R + tr) & 127;
            const int sc = (tc + R - 16) & 127;
            b_lds[(ci * ROWS + tr) * 152 + tc] =
                f2bf(xpsi[((((size_t)J2*4 + b)*8) + ch2lo + ci) * 16384 + sr * 128 + sc]);
        }
    }

    // ---- A stage: [m<MV][2 K-rows x 128px], 16B-granule swizzle lo = (o&31)^(m&15) ----
    auto stageA = [&](int sub, int bufi) {
        unsigned short* ab = a_lds + bufi * ABUF;
        constexpr int ng = MV * 32;               // 16B granules, ng % 256 == 0
        #pragma unroll
        for (int it = 0; it < ng / TPB; ++it) {
            const int o  = it * TPB + tid;
            const int m  = o >> 5;
            const int lo = (o & 31) ^ (m & 15);
            const int j1 = m >> 3, ch1 = m & 7;
            if (PRE) {
                const unsigned short* src = xbf + ((((size_t)j1*4 + b)*8) + ch1) * 16384
                    + (k0 + sub * 2 + (lo >> 4)) * 128 + ((lo & 15) << 3);
                __builtin_amdgcn_global_load_lds((gu32*)src, (lu32*)(ab + o * 8), 16, 0, 0);
            } else {
                const float* s = xpsi + ((((size_t)j1*4 + b)*8) + ch1) * 16384
                               + (k0 + sub * 2 + (lo >> 4)) * 128 + ((lo & 15) << 3);
                const float4 f0 = ((const float4*)s)[0];
                const float4 f1 = ((const float4*)s)[1];
                *(ushort4*)(ab + o * 8)     = ushort4{f2bf(f0.x), f2bf(f0.y), f2bf(f0.z), f2bf(f0.w)};
                *(ushort4*)(ab + o * 8 + 4) = ushort4{f2bf(f1.x), f2bf(f1.y), f2bf(f1.z), f2bf(f1.w)};
            }
        }
    };

    float4v acc0[DYN], acc1[DYN];
    #pragma unroll
    for (int i = 0; i < DYN; ++i) { acc0[i] = (float4v)0.f; acc1[i] = (float4v)0.f; }

    auto compute = [&](int sub, int bufi) {
        const char* abase = (const char*)(a_lds + bufi * ABUF);
        #pragma unroll
        for (int i2 = 0; i2 < 2; ++i2) {          // ks = wv + 4*i2
            const int loff = (((i2 << 8) | (wv << 6) | (g << 4))) ^ ((c & 15) << 4);
            short8 af0 = {0,0,0,0,0,0,0,0};
            short8 af1 = {0,0,0,0,0,0,0,0};
            if (MV >= 16 || c < MV)
                af0 = *(const short8*)(abase + c * 512 + loff);
            if (F == 2 && (MV >= 32 || c + 16 < MV))
                af1 = *(const short8*)(abase + (c + 16) * 512 + loff);

            const unsigned short* bp = b_lds + bst + (sub * 2 + i2) * 152
                                     + (wv << 5) + (g << 3);
            const uint4 wA = *(const uint4*)bp;
            const uint4 wB = *(const uint4*)(bp + 8);
            const uint4 wC = *(const uint4*)(bp + 16);
            const unsigned int wd[12] = {wA.x,wA.y,wA.z,wA.w, wB.x,wB.y,wB.z,wB.w,
                                         wC.x,wC.y,wC.z,wC.w};
            #pragma unroll
            for (int dyi = 0; dyi < DYN; ++dyi) {
                unsigned int o0, o1, o2, o3;
                if ((dyi & 1) == 0) {
                    const int bb = 8 - (dyi >> 1);
                    o0 = wd[bb]; o1 = wd[bb+1]; o2 = wd[bb+2]; o3 = wd[bb+3];
                } else {
                    const int bb = (15 - dyi) >> 1;        // v_alignbit pattern
                    o0 = (wd[bb]   >> 16) | (wd[bb+1] << 16);
                    o1 = (wd[bb+1] >> 16) | (wd[bb+2] << 16);
                    o2 = (wd[bb+2] >> 16) | (wd[bb+3] << 16);
                    o3 = (wd[bb+3] >> 16) | (wd[bb+4] << 16);
                }
                union { unsigned int u[4]; short8 s; } bq;
                bq.u[0] = o0; bq.u[1] = o1; bq.u[2] = o2; bq.u[3] = o3;
                acc0[dyi] = __builtin_amdgcn_mfma_f32_16x16x32_bf16(
                    af0, bq.s, acc0[dyi], 0, 0, 0);
                if (F == 2)
                    acc1[dyi] = __builtin_amdgcn_mfma_f32_16x16x32_bf16(
                        af1, bq.s, acc1[dyi], 0, 0, 0);
            }
        }
    };

    stageA(0, 0);
    __syncthreads();
    for (int sub = 0; sub < 8; ++sub) {
        if (sub < 7) stageA(sub + 1, (sub + 1) & 1);   // async prefetch under compute
        compute(sub, sub & 1);
        __syncthreads();
    }

    if (!validn) return;

    if (PART) {
        // partial[t][kc][wv][b][dyi][m][c] — plain coalesced stores, no contention
        float* pt = part + TBASE[tglob] + (size_t)((kc * 4 + wv) * 4 + b) * S;
        #pragma unroll
        for (int dyi = 0; dyi < DYN; ++dyi) {
            #pragma unroll
            for (int f = 0; f < F; ++f) {
                #pragma unroll
                for (int t2 = 0; t2 < 4; ++t2) {
                    const int m = (g << 2) + t2 + (f << 4);
                    if (m >= MV) continue;
                    pt[(dyi * MV + m) * 16 + c] = f ? acc1[dyi][t2] : acc0[dyi][t2];
                }
            }
        }
    } else {
        #pragma unroll
        for (int dyi = 0; dyi < DYN; ++dyi) {
            const int dy = dyi - R;
            const int yo = dy < 0 ? dy + 17 : dy;
            #pragma unroll
            for (int f = 0; f < F; ++f) {
                #pragma unroll
                for (int t2 = 0; t2 < 4; ++t2) {
                    const int m = (g << 2) + t2 + (f << 4);
                    if (m >= MV) continue;
                    const int j1 = m >> 3, ch1 = m & 7;
                    const int pb = ((j1 * (9 - j1)) >> 1) + (J2 - j1);
                    const int p  = pb * 64 + ((ch1 >> 1) << 4) + ((ch2 >> 1) << 2)
                                 + ((ch1 & 1) << 1) + (ch2 & 1);
                    const float val = f ? acc1[dyi][t2] : acc0[dyi][t2];
                    atomicAdd(out + (size_t)(p * 4 + b) * 289 + xo * 17 + yo, val);
                }
            }
        }
    }
}

template<bool PRE, bool PART>
__global__ __launch_bounds__(TPB, 2)
void corr_v5(const float* __restrict__ xpsi, const unsigned short* __restrict__ xbf,
             float* __restrict__ out, float* __restrict__ part)
{
    __shared__ __align__(16) unsigned char smem[52224];
    const int bid = blockIdx.x;
    const int t   = bid % 19;          // tiles j2-descending -> heavy blocks first
    const int rem = bid / 19;
    const int b   = rem & 3;
    const int kc  = rem >> 2;
    if (t < 9)       corr_body<3, PRE, PART>(xpsi, xbf, out, part, smem, t, t,      b, kc);
    else if (t < 14) corr_body<2, PRE, PART>(xpsi, xbf, out, part, smem, t, t - 9,  b, kc);
    else if (t < 17) corr_body<1, PRE, PART>(xpsi, xbf, out, part, smem, t, t - 14, b, kc);
    else             corr_body<0, PRE, PART>(xpsi, xbf, out, part, smem, t, t - 17, b, kc);
}

// sum the 32 (kc,wv) partial slices; float4 over 4 consecutive c; out pre-zeroed.
__global__ __launch_bounds__(256)
void reduce2(const float* __restrict__ part, float* __restrict__ out)
{
    const int t  = blockIdx.y;
    const int j2 = (t < 9) ? 3 : (t < 14) ? 2 : (t < 17) ? 1 : 0;
    const int nt = t - ((t < 9) ? 0 : (t < 14) ? 9 : (t < 17) ? 14 : 17);
    const int R = 1 << j2, DXN = 2 * R + 1, DYN = DXN, MV = 8 * (j2 + 1);
    const int S = DYN * MV * 16;
    const int tot = 4 * DYN * MV * 4;            // b * dyi * m * c4
    const int i = blockIdx.x * 256 + threadIdx.x;
    if (i >= tot) return;
    const int c4 = (i & 3) << 2;
    int r2 = i >> 2;
    const int m = r2 % MV;  r2 /= MV;
    const int dyi = r2 % DYN;
    const int b   = r2 / DYN;
    const int ncol0 = nt * 16 + c4;
    if (ncol0 >= 8 * DXN) return;
    const float* q = part + TBASE[t] + (size_t)b * S + (dyi * MV + m) * 16 + c4;
    float4 v = {0.f, 0.f, 0.f, 0.f};
    for (int qq = 0; qq < 32; ++qq) {
        const float4 w = *(const float4*)(q + (size_t)qq * 4 * S);
        v.x += w.x; v.y += w.y; v.z += w.z; v.w += w.w;
    }
    const int dy = dyi - R;
    const int yo = dy < 0 ? dy + 17 : dy;
    const int j1 = m >> 3, ch1 = m & 7;
    const int pb = ((j1 * (9 - j1)) >> 1) + (j2 - j1);
    const float vv[4] = {v.x, v.y, v.z, v.w};
    #pragma unroll
    for (int e = 0; e < 4; ++e) {
        const int ncol = ncol0 + e;
        if (ncol >= 8 * DXN) break;
        const int ch2 = ncol / DXN;
        const int dxi = ncol - ch2 * DXN;
        const int dx  = dxi - R;
        const int xo  = dx < 0 ? dx + 17 : dx;
        const int p   = pb * 64 + ((ch1 >> 1) << 4) + ((ch2 >> 1) << 2)
                      + ((ch1 & 1) << 1) + (ch2 & 1);
        out[(size_t)(p * 4 + b) * 289 + xo * 17 + yo] = vv[e];
    }
}

extern "C" void kernel_launch(void* const* d_in, const int* in_sizes, int n_in,
                              void* d_out, int out_size, void* d_ws, size_t ws_size,
                              hipStream_t stream) {
    const float* xpsi = (const float*)d_in[0];
    float* out = (float*)d_out;

    if (ws_size >= (size_t)PBYTE + (size_t)NPART * 4) {
        unsigned short* xbf = (unsigned short*)d_ws;
        float* part = (float*)((char*)d_ws + PBYTE);
        hipMemsetAsync(d_out, 0, (size_t)out_size * sizeof(float), stream);
        conv_bf16<<<(NGR + ZPG + 255) / 256, 256, 0, stream>>>(xpsi, xbf);
        corr_v5<true, true><<<608, TPB, 0, stream>>>(xpsi, xbf, out, part);
        reduce2<<<dim3(34, 19), 256, 0, stream>>>(part, out);
    } else if (ws_size >= (size_t)PBYTE) {
        unsigned short* xbf = (unsigned short*)d_ws;
        hipMemsetAsync(d_out, 0, (size_t)out_size * sizeof(float), stream);
        conv_bf16<<<(NGR + ZPG + 255) / 256, 256, 0, stream>>>(xpsi, xbf);
        corr_v5<true, false><<<608, TPB, 0, stream>>>(xpsi, xbf, out, nullptr);
    } else {
        hipMemsetAsync(d_out, 0, (size_t)out_size * sizeof(float), stream);
        corr_v5<false, false><<<608, TPB, 0, stream>>>(xpsi, nullptr, out, nullptr);
    }
}

// Round 6
// 52.481 us; speedup vs baseline: 8.0790x; 1.0742x over previous
//
#include <hip/hip_runtime.h>

typedef __attribute__((ext_vector_type(8))) short short8;
typedef __attribute__((ext_vector_type(4))) float float4v;
typedef __attribute__((address_space(1))) const unsigned int gu32;
typedef __attribute__((address_space(3))) unsigned int lu32;

#define TPB 256
#define NXPSI (4*4*8*16384)      /* 2097152 fp32 elements */
#define NGR   (NXPSI/4)          /* 524288 float4 granules */
#define ZPG   64                 /* zero-page ushort4 granules -> 512B */
#define PBYTE (NXPSI*2 + ZPG*8)  /* partial region byte offset = 4194816 */
#define NPART 12828672           /* partial floats: 32 (kc,wv) slices */
#define NOUT  739840             /* 640*4*289 */
#define NTILE 34

// per-partial-tile base (floats), 19 tiles as in R4/R5. size(t) = 32*4*DYN*MV*16
__device__ __constant__ int TBASE[19] = {
    0, 1114112, 2228224, 3342336, 4456448, 5570560, 6684672, 7798784, 8912896,
    10027008, 10469376, 10911744, 11354112, 11796480,
    12238848, 12402688, 12566528,
    12730368, 12779520};

// 34 block-tiles: 18x(J2=3 m-split), 10x(J2=2 m-split), 3x(J2=1), 3x(J2=0 8-wide)
__device__ __constant__ unsigned char TN0[NTILE] = {
    0,0,16,16,32,32,48,48,64,64,80,80,96,96,112,112,128,128,
    0,0,16,16,32,32,48,48,64,64,
    0,16,32,
    0,8,16};
__device__ __constant__ unsigned char TMOFF[NTILE] = {
    0,16,0,16,0,16,0,16,0,16,0,16,0,16,0,16,0,16,
    0,16,0,16,0,16,0,16,0,16,
    0,0,0,
    0,0,0};
__device__ __constant__ unsigned char TGL[NTILE] = {
    0,0,1,1,2,2,3,3,4,4,5,5,6,6,7,7,8,8,
    9,9,10,10,11,11,12,12,13,13,
    14,15,16,
    17,17,18};

static __device__ __forceinline__ unsigned short f2bf(float f) {
    unsigned int u = __builtin_bit_cast(unsigned int, f);
    u = (u + 0x7FFFu + ((u >> 16) & 1u)) >> 16;     // RNE, data has no NaN
    return (unsigned short)u;
}

__global__ __launch_bounds__(256)
void conv_bf16(const float* __restrict__ in, unsigned short* __restrict__ outw) {
    const int g = blockIdx.x * 256 + threadIdx.x;
    if (g < NGR) {
        const float4 v = reinterpret_cast<const float4*>(in)[g];
        reinterpret_cast<ushort4*>(outw)[g] =
            ushort4{f2bf(v.x), f2bf(v.y), f2bf(v.z), f2bf(v.w)};
    } else if (g < NGR + ZPG) {
        reinterpret_cast<ushort4*>(outw)[g] = ushort4{0, 0, 0, 0};
    }
}

// corr[p,b,dx,dy] = sum_{u,v} a[u,v]*b[(u-dx)%128,(v-dy)%128]; nonzero |dx|,|dy|<=r=2^j2.
// Waves split K (wave wv owns K-slices wv, wv+4). Each block: 16 A-rows (m-half).
template<int J2, bool PRE, bool PART>
static __device__ __forceinline__ void corr_body(
        const float* __restrict__ xpsi, const unsigned short* __restrict__ xbf,
        float* __restrict__ out, float* __restrict__ part,
        unsigned char* smem, int tgl, int n0, int moff, int b, int kc)
{
    constexpr int R    = 1 << J2;
    constexpr int DXN  = 2 * R + 1;
    constexpr int DYN  = DXN;
    constexpr int MV   = 8 * (J2 + 1);            // class m-rows (partial layout)
    constexpr int ROWS = 16 + 2 * R;              // B row window
    constexpr int ABUF = 16 * 256;                // elements per A buffer (16 rows x 2 K-rows)
    constexpr int S    = DYN * MV * 16;           // floats per partial slice
    constexpr int W    = (J2 == 0) ? 8 : 16;      // n-tile width

    unsigned short* a_lds = (unsigned short*)smem;               // 2 x ABUF el
    unsigned short* b_lds = (unsigned short*)(smem + 4 * ABUF);  // byte offset 16384

    const int k0    = kc * 16;
    const int vrows = (MV - moff < 16) ? MV - moff : 16;         // valid staged rows

    const int ch2lo = n0 / DXN;
    int nhi = n0 + W - 1; if (nhi > 8 * DXN - 1) nhi = 8 * DXN - 1;
    const int nimg = nhi / DXN - ch2lo + 1;

    const int tid  = threadIdx.x;
    const int lane = tid & 63;
    const int wv   = tid >> 6;
    const int c    = lane & 15;       // N-col in tile / A m-row
    const int g    = lane >> 4;       // K-group

    const int ncol    = n0 + c;
    const bool validn = (ncol < 8 * DXN) && (J2 > 0 || c < 8);
    const int ncc     = validn ? ncol : n0;
    const int ch2     = ncc / DXN;
    const int dxi     = ncc - ch2 * DXN;
    const int dx      = dxi - R;
    const int xo      = dx < 0 ? dx + 17 : dx;
    const int bst     = ((ch2 - ch2lo) * ROWS + (2 * R - dxi)) * 152;

    // ---- A stage: 16 rows x [2 K-rows x 128px], granule swizzle lo=(o&31)^(ms&15) ----
    auto stageA = [&](int sub, int bufi) {
        unsigned short* ab = a_lds + bufi * ABUF;
        #pragma unroll
        for (int it = 0; it < 2; ++it) {          // 512 granules / 256 threads
            const int o  = it * TPB + tid;
            const int ms = o >> 5;
            const int lo = (o & 31) ^ ms;
            const int me = moff + ms;
            const int j1 = me >> 3, ch1 = me & 7;
            if (PRE) {
                const unsigned short* src = (ms < vrows)
                    ? xbf + ((((size_t)j1*4 + b)*8) + ch1) * 16384
                          + (k0 + sub * 2 + (lo >> 4)) * 128 + ((lo & 15) << 3)
                    : xbf + NXPSI + ((lo & 31) << 3);          // zero page
                __builtin_amdgcn_global_load_lds((gu32*)src, (lu32*)(ab + o * 8), 16, 0, 0);
            } else {
                ushort4 w0{0,0,0,0}, w1{0,0,0,0};
                if (ms < vrows) {
                    const float* s = xpsi + ((((size_t)j1*4 + b)*8) + ch1) * 16384
                                   + (k0 + sub * 2 + (lo >> 4)) * 128 + ((lo & 15) << 3);
                    const float4 f0 = ((const float4*)s)[0];
                    const float4 f1 = ((const float4*)s)[1];
                    w0 = ushort4{f2bf(f0.x), f2bf(f0.y), f2bf(f0.z), f2bf(f0.w)};
                    w1 = ushort4{f2bf(f1.x), f2bf(f1.y), f2bf(f1.z), f2bf(f1.w)};
                }
                *(ushort4*)(ab + o * 8)     = w0;
                *(ushort4*)(ab + o * 8 + 4) = w1;
            }
        }
    };

    // issue first A-chunk (async) before B staging so it flies underneath
    stageA(0, 0);

    // ---- stage B once: [nimg][ROWS][144 +8pad], col tc <-> src (tc+R-16)&127 ----
    if (PRE && J2 >= 2) {
        // wrap boundary 4-aligned for R in {4,8} -> clean ushort4 granules
        for (int ci = 0; ci < nimg; ++ci) {
            const unsigned short* img = xbf + ((((size_t)J2*4 + b)*8) + ch2lo + ci) * 16384;
            const int ng2 = ROWS * 36;
            for (int i = tid; i < ng2; i += TPB) {
                const int tr = i / 36, tc = (i - tr * 36) * 4;
                const int sr = (k0 - R + tr) & 127;
                const int sc = (tc + R - 16) & 127;
                *(ushort4*)(b_lds + (ci * ROWS + tr) * 152 + tc) =
                    *(const ushort4*)(img + sr * 128 + sc);
            }
        }
    } else {
        const int tot = nimg * ROWS * 144;
        for (int i = tid; i < tot; i += TPB) {
            const int ci = i / (ROWS * 144);
            const int rr = i - ci * (ROWS * 144);
            const int tr = rr / 144, tc = rr - tr * 144;
            const int sr = (k0 - R + tr) & 127;
            const int sc = (tc + R - 16) & 127;
            b_lds[(ci * ROWS + tr) * 152 + tc] = PRE
                ? xbf[((((size_t)J2*4 + b)*8) + ch2lo + ci) * 16384 + sr * 128 + sc]
                : f2bf(xpsi[((((size_t)J2*4 + b)*8) + ch2lo + ci) * 16384 + sr * 128 + sc]);
        }
    }

    float4v acc[DYN];
    #pragma unroll
    for (int i = 0; i < DYN; ++i) acc[i] = (float4v)0.f;

    auto compute = [&](int sub, int bufi) {
        const char* abase = (const char*)(a_lds + bufi * ABUF);
        #pragma unroll
        for (int i2 = 0; i2 < 2; ++i2) {          // K-slice = wv + 4*i2
            const int loff = (((i2 << 8) | (wv << 6) | (g << 4))) ^ (c << 4);
            const short8 af0 = *(const short8*)(abase + c * 512 + loff);

            const unsigned short* bp = b_lds + bst + (sub * 2 + i2) * 152
                                     + (wv << 5) + (g << 3);
            const uint4 wA = *(const uint4*)bp;
            const uint4 wB = *(const uint4*)(bp + 8);
            const uint4 wC = *(const uint4*)(bp + 16);
            const unsigned int wd[12] = {wA.x,wA.y,wA.z,wA.w, wB.x,wB.y,wB.z,wB.w,
                                         wC.x,wC.y,wC.z,wC.w};
            #pragma unroll
            for (int dyi = 0; dyi < DYN; ++dyi) {
                unsigned int o0, o1, o2, o3;
                if ((dyi & 1) == 0) {
                    const int bb = 8 - (dyi >> 1);
                    o0 = wd[bb]; o1 = wd[bb+1]; o2 = wd[bb+2]; o3 = wd[bb+3];
                } else {
                    const int bb = (15 - dyi) >> 1;        // v_alignbit pattern
                    o0 = (wd[bb]   >> 16) | (wd[bb+1] << 16);
                    o1 = (wd[bb+1] >> 16) | (wd[bb+2] << 16);
                    o2 = (wd[bb+2] >> 16) | (wd[bb+3] << 16);
                    o3 = (wd[bb+3] >> 16) | (wd[bb+4] << 16);
                }
                union { unsigned int u[4]; short8 s; } bq;
                bq.u[0] = o0; bq.u[1] = o1; bq.u[2] = o2; bq.u[3] = o3;
                acc[dyi] = __builtin_amdgcn_mfma_f32_16x16x32_bf16(
                    af0, bq.s, acc[dyi], 0, 0, 0);
            }
        }
    };

    __syncthreads();
    for (int sub = 0; sub < 8; ++sub) {
        if (sub < 7) stageA(sub + 1, (sub + 1) & 1);   // async prefetch under compute
        compute(sub, sub & 1);
        __syncthreads();
    }

    if (!validn) return;
    const int cpart = (n0 & 15) + c;

    if (PART) {
        // partial[tgl][kc][wv][b][dyi][m][c] — plain coalesced stores, no contention
        float* pt = part + TBASE[tgl] + (size_t)((kc * 4 + wv) * 4 + b) * S;
        #pragma unroll
        for (int dyi = 0; dyi < DYN; ++dyi) {
            #pragma unroll
            for (int t2 = 0; t2 < 4; ++t2) {
                const int ml = (g << 2) + t2;
                if (ml >= vrows) continue;
                pt[(dyi * MV + moff + ml) * 16 + cpart] = acc[dyi][t2];
            }
        }
    } else {
        #pragma unroll
        for (int dyi = 0; dyi < DYN; ++dyi) {
            const int dy = dyi - R;
            const int yo = dy < 0 ? dy + 17 : dy;
            #pragma unroll
            for (int t2 = 0; t2 < 4; ++t2) {
                const int ml = (g << 2) + t2;
                if (ml >= vrows) continue;
                const int m = moff + ml;
                const int j1 = m >> 3, ch1 = m & 7;
                const int pb = ((j1 * (9 - j1)) >> 1) + (J2 - j1);
                const int p  = pb * 64 + ((ch1 >> 1) << 4) + ((ch2 >> 1) << 2)
                             + ((ch1 & 1) << 1) + (ch2 & 1);
                atomicAdd(out + (size_t)(p * 4 + b) * 289 + xo * 17 + yo, acc[dyi][t2]);
            }
        }
    }
}

template<bool PRE, bool PART>
__global__ __launch_bounds__(TPB, 3)
void corr_v6(const float* __restrict__ xpsi, const unsigned short* __restrict__ xbf,
             float* __restrict__ out, float* __restrict__ part)
{
    __shared__ __align__(16) unsigned char smem[40704];
    const int bid = blockIdx.x;
    const int t   = bid % NTILE;       // heavy classes first
    const int rem = bid / NTILE;
    const int b   = rem & 3;
    const int kc  = rem >> 2;
    const int n0   = TN0[t];
    const int moff = TMOFF[t];
    const int tgl  = TGL[t];
    if (t < 18)      corr_body<3, PRE, PART>(xpsi, xbf, out, part, smem, tgl, n0, moff, b, kc);
    else if (t < 28) corr_body<2, PRE, PART>(xpsi, xbf, out, part, smem, tgl, n0, moff, b, kc);
    else if (t < 31) corr_body<1, PRE, PART>(xpsi, xbf, out, part, smem, tgl, n0, moff, b, kc);
    else             corr_body<0, PRE, PART>(xpsi, xbf, out, part, smem, tgl, n0, moff, b, kc);
}

// sum the 32 (kc,wv) partial slices; float4 over 4 consecutive c; unchanged from R5.
__global__ __launch_bounds__(256)
void reduce2(const float* __restrict__ part, float* __restrict__ out)
{
    const int t  = blockIdx.y;
    const int j2 = (t < 9) ? 3 : (t < 14) ? 2 : (t < 17) ? 1 : 0;
    const int nt = t - ((t < 9) ? 0 : (t < 14) ? 9 : (t < 17) ? 14 : 17);
    const int R = 1 << j2, DXN = 2 * R + 1, DYN = DXN, MV = 8 * (j2 + 1);
    const int S = DYN * MV * 16;
    const int tot = 4 * DYN * MV * 4;            // b * dyi * m * c4
    const int i = blockIdx.x * 256 + threadIdx.x;
    if (i >= tot) return;
    const int c4 = (i & 3) << 2;
    int r2 = i >> 2;
    const int m = r2 % MV;  r2 /= MV;
    const int dyi = r2 % DYN;
    const int b   = r2 / DYN;
    const int ncol0 = nt * 16 + c4;
    if (ncol0 >= 8 * DXN) return;
    const float* q = part + TBASE[t] + (size_t)b * S + (dyi * MV + m) * 16 + c4;
    float4 v = {0.f, 0.f, 0.f, 0.f};
    for (int qq = 0; qq < 32; ++qq) {
        const float4 w = *(const float4*)(q + (size_t)qq * 4 * S);
        v.x += w.x; v.y += w.y; v.z += w.z; v.w += w.w;
    }
    const int dy = dyi - R;
    const int yo = dy < 0 ? dy + 17 : dy;
    const int j1 = m >> 3, ch1 = m & 7;
    const int pb = ((j1 * (9 - j1)) >> 1) + (j2 - j1);
    const float vv[4] = {v.x, v.y, v.z, v.w};
    #pragma unroll
    for (int e = 0; e < 4; ++e) {
        const int ncol = ncol0 + e;
        if (ncol >= 8 * DXN) break;
        const int ch2 = ncol / DXN;
        const int dxi = ncol - ch2 * DXN;
        const int dx  = dxi - R;
        const int xo  = dx < 0 ? dx + 17 : dx;
        const int p   = pb * 64 + ((ch1 >> 1) << 4) + ((ch2 >> 1) << 2)
                      + ((ch1 & 1) << 1) + (ch2 & 1);
        out[(size_t)(p * 4 + b) * 289 + xo * 17 + yo] = vv[e];
    }
}

extern "C" void kernel_launch(void* const* d_in, const int* in_sizes, int n_in,
                              void* d_out, int out_size, void* d_ws, size_t ws_size,
                              hipStream_t stream) {
    const float* xpsi = (const float*)d_in[0];
    float* out = (float*)d_out;

    if (ws_size >= (size_t)PBYTE + (size_t)NPART * 4) {
        unsigned short* xbf = (unsigned short*)d_ws;
        float* part = (float*)((char*)d_ws + PBYTE);
        hipMemsetAsync(d_out, 0, (size_t)out_size * sizeof(float), stream);
        conv_bf16<<<(NGR + ZPG + 255) / 256, 256, 0, stream>>>(xpsi, xbf);
        corr_v6<true, true><<<NTILE * 32, TPB, 0, stream>>>(xpsi, xbf, out, part);
        reduce2<<<dim3(34, 19), 256, 0, stream>>>(part, out);
    } else if (ws_size >= (size_t)PBYTE) {
        unsigned short* xbf = (unsigned short*)d_ws;
        hipMemsetAsync(d_out, 0, (size_t)out_size * sizeof(float), stream);
        conv_bf16<<<(NGR + ZPG + 255) / 256, 256, 0, stream>>>(xpsi, xbf);
        corr_v6<true, false><<<NTILE * 32, TPB, 0, stream>>>(xpsi, xbf, out, nullptr);
    } else {
        hipMemsetAsync(d_out, 0, (size_t)out_size * sizeof(float), stream);
        corr_v6<false, false><<<NTILE * 32, TPB, 0, stream>>>(xpsi, nullptr, out, nullptr);
    }
}

// Round 7
// 47.033 us; speedup vs baseline: 9.0149x; 1.1158x over previous
//
#include <hip/hip_runtime.h>

typedef __attribute__((ext_vector_type(8))) short short8;
typedef __attribute__((ext_vector_type(4))) float float4v;
typedef __attribute__((address_space(1))) const unsigned int gu32;
typedef __attribute__((address_space(3))) unsigned int lu32;

#define TPB 256
#define NXPSI (4*4*8*16384)      /* 2097152 fp32 elements */
#define NGR   (NXPSI/4)          /* 524288 float4 granules */
#define ZPG   64                 /* zero-page ushort4 granules -> 512B */
#define PBYTE (NXPSI*2 + ZPG*8)  /* partial region byte offset = 4194816 */
#define NPART 3207168            /* partial floats: 8 kc-slices (in-block wv-reduced) */
#define NOUT  739840             /* 640*4*289 */
#define NTILE 34

// per-partial-tile base (floats), 19 tiles. size(t) = 8*4*DYN*MV*16
__device__ __constant__ int TBASE[19] = {
    0, 278528, 557056, 835584, 1114112, 1392640, 1671168, 1949696, 2228224,
    2506752, 2617344, 2727936, 2838528, 2949120,
    3059712, 3100672, 3141632,
    3182592, 3194880};

// 34 block-tiles: 18x(J2=3 m-split), 10x(J2=2 m-split), 3x(J2=1), 3x(J2=0 8-wide)
__device__ __constant__ unsigned char TN0[NTILE] = {
    0,0,16,16,32,32,48,48,64,64,80,80,96,96,112,112,128,128,
    0,0,16,16,32,32,48,48,64,64,
    0,16,32,
    0,8,16};
__device__ __constant__ unsigned char TMOFF[NTILE] = {
    0,16,0,16,0,16,0,16,0,16,0,16,0,16,0,16,0,16,
    0,16,0,16,0,16,0,16,0,16,
    0,0,0,
    0,0,0};
__device__ __constant__ unsigned char TGL[NTILE] = {
    0,0,1,1,2,2,3,3,4,4,5,5,6,6,7,7,8,8,
    9,9,10,10,11,11,12,12,13,13,
    14,15,16,
    17,17,18};

static __device__ __forceinline__ unsigned short f2bf(float f) {
    unsigned int u = __builtin_bit_cast(unsigned int, f);
    u = (u + 0x7FFFu + ((u >> 16) & 1u)) >> 16;     // RNE, data has no NaN
    return (unsigned short)u;
}

__global__ __launch_bounds__(256)
void conv_bf16(const float* __restrict__ in, unsigned short* __restrict__ outw) {
    const int g = blockIdx.x * 256 + threadIdx.x;
    if (g < NGR) {
        const float4 v = reinterpret_cast<const float4*>(in)[g];
        reinterpret_cast<ushort4*>(outw)[g] =
            ushort4{f2bf(v.x), f2bf(v.y), f2bf(v.z), f2bf(v.w)};
    } else if (g < NGR + ZPG) {
        reinterpret_cast<ushort4*>(outw)[g] = ushort4{0, 0, 0, 0};
    }
}

// corr[p,b,dx,dy] = sum_{u,v} a[u,v]*b[(u-dx)%128,(v-dy)%128]; nonzero |dx|,|dy|<=r=2^j2.
// Waves split K (wave wv owns K-slices wv, wv+4); cross-wave sum via LDS before store.
template<int J2, bool PRE, bool PART>
static __device__ __forceinline__ void corr_body(
        const float* __restrict__ xpsi, const unsigned short* __restrict__ xbf,
        float* __restrict__ out, float* __restrict__ part,
        unsigned char* smem, int tgl, int n0, int moff, int b, int kc)
{
    constexpr int R    = 1 << J2;
    constexpr int DXN  = 2 * R + 1;
    constexpr int DYN  = DXN;
    constexpr int MV   = 8 * (J2 + 1);            // class m-rows (partial layout)
    constexpr int ROWS = 16 + 2 * R;              // B row window
    constexpr int ABUF = 16 * 256;                // elements per A buffer (16 rows x 2 K-rows)
    constexpr int S    = DYN * MV * 16;           // floats per partial slice
    constexpr int W    = (J2 == 0) ? 8 : 16;      // n-tile width

    unsigned short* a_lds = (unsigned short*)smem;               // 2 x ABUF el
    unsigned short* b_lds = (unsigned short*)(smem + 4 * ABUF);  // byte offset 16384

    const int k0    = kc * 16;
    const int vrows = (MV - moff < 16) ? MV - moff : 16;         // valid staged rows

    const int ch2lo = n0 / DXN;
    int nhi = n0 + W - 1; if (nhi > 8 * DXN - 1) nhi = 8 * DXN - 1;
    const int nimg = nhi / DXN - ch2lo + 1;

    const int tid  = threadIdx.x;
    const int lane = tid & 63;
    const int wv   = tid >> 6;
    const int c    = lane & 15;       // N-col in tile / A m-row
    const int g    = lane >> 4;       // K-group

    const int ncol    = n0 + c;
    const bool validn = (ncol < 8 * DXN) && (J2 > 0 || c < 8);
    const int ncc     = validn ? ncol : n0;
    const int ch2     = ncc / DXN;
    const int dxi     = ncc - ch2 * DXN;
    const int dx      = dxi - R;
    const int xo      = dx < 0 ? dx + 17 : dx;
    const int bst     = ((ch2 - ch2lo) * ROWS + (2 * R - dxi)) * 152;

    // ---- A stage: 16 rows x [2 K-rows x 128px], granule swizzle lo=(o&31)^(ms&15) ----
    auto stageA = [&](int sub, int bufi) {
        unsigned short* ab = a_lds + bufi * ABUF;
        #pragma unroll
        for (int it = 0; it < 2; ++it) {          // 512 granules / 256 threads
            const int o  = it * TPB + tid;
            const int ms = o >> 5;
            const int lo = (o & 31) ^ ms;
            const int me = moff + ms;
            const int j1 = me >> 3, ch1 = me & 7;
            if (PRE) {
                const unsigned short* src = (ms < vrows)
                    ? xbf + ((((size_t)j1*4 + b)*8) + ch1) * 16384
                          + (k0 + sub * 2 + (lo >> 4)) * 128 + ((lo & 15) << 3)
                    : xbf + NXPSI + ((lo & 31) << 3);          // zero page
                __builtin_amdgcn_global_load_lds((gu32*)src, (lu32*)(ab + o * 8), 16, 0, 0);
            } else {
                ushort4 w0{0,0,0,0}, w1{0,0,0,0};
                if (ms < vrows) {
                    const float* s = xpsi + ((((size_t)j1*4 + b)*8) + ch1) * 16384
                                   + (k0 + sub * 2 + (lo >> 4)) * 128 + ((lo & 15) << 3);
                    const float4 f0 = ((const float4*)s)[0];
                    const float4 f1 = ((const float4*)s)[1];
                    w0 = ushort4{f2bf(f0.x), f2bf(f0.y), f2bf(f0.z), f2bf(f0.w)};
                    w1 = ushort4{f2bf(f1.x), f2bf(f1.y), f2bf(f1.z), f2bf(f1.w)};
                }
                *(ushort4*)(ab + o * 8)     = w0;
                *(ushort4*)(ab + o * 8 + 4) = w1;
            }
        }
    };

    // issue first A-chunk (async) before B staging so it flies underneath
    stageA(0, 0);

    // ---- stage B once: [nimg][ROWS][144 +8pad], col tc <-> src (tc+R-16)&127 ----
    if (PRE && J2 >= 2) {
        // wrap boundary 4-aligned for R in {4,8} -> clean ushort4 granules
        for (int ci = 0; ci < nimg; ++ci) {
            const unsigned short* img = xbf + ((((size_t)J2*4 + b)*8) + ch2lo + ci) * 16384;
            const int ng2 = ROWS * 36;
            for (int i = tid; i < ng2; i += TPB) {
                const int tr = i / 36, tc = (i - tr * 36) * 4;
                const int sr = (k0 - R + tr) & 127;
                const int sc = (tc + R - 16) & 127;
                *(ushort4*)(b_lds + (ci * ROWS + tr) * 152 + tc) =
                    *(const ushort4*)(img + sr * 128 + sc);
            }
        }
    } else {
        const int tot = nimg * ROWS * 144;
        for (int i = tid; i < tot; i += TPB) {
            const int ci = i / (ROWS * 144);
            const int rr = i - ci * (ROWS * 144);
            const int tr = rr / 144, tc = rr - tr * 144;
            const int sr = (k0 - R + tr) & 127;
            const int sc = (tc + R - 16) & 127;
            b_lds[(ci * ROWS + tr) * 152 + tc] = PRE
                ? xbf[((((size_t)J2*4 + b)*8) + ch2lo + ci) * 16384 + sr * 128 + sc]
                : f2bf(xpsi[((((size_t)J2*4 + b)*8) + ch2lo + ci) * 16384 + sr * 128 + sc]);
        }
    }

    float4v acc[DYN];
    #pragma unroll
    for (int i = 0; i < DYN; ++i) acc[i] = (float4v)0.f;

    auto compute = [&](int sub, int bufi) {
        const char* abase = (const char*)(a_lds + bufi * ABUF);
        #pragma unroll
        for (int i2 = 0; i2 < 2; ++i2) {          // K-slice = wv + 4*i2
            const int loff = (((i2 << 8) | (wv << 6) | (g << 4))) ^ (c << 4);
            const short8 af0 = *(const short8*)(abase + c * 512 + loff);

            const unsigned short* bp = b_lds + bst + (sub * 2 + i2) * 152
                                     + (wv << 5) + (g << 3);
            const uint4 wA = *(const uint4*)bp;
            const uint4 wB = *(const uint4*)(bp + 8);
            const uint4 wC = *(const uint4*)(bp + 16);
            const unsigned int wd[12] = {wA.x,wA.y,wA.z,wA.w, wB.x,wB.y,wB.z,wB.w,
                                         wC.x,wC.y,wC.z,wC.w};
            #pragma unroll
            for (int dyi = 0; dyi < DYN; ++dyi) {
                unsigned int o0, o1, o2, o3;
                if ((dyi & 1) == 0) {
                    const int bb = 8 - (dyi >> 1);
                    o0 = wd[bb]; o1 = wd[bb+1]; o2 = wd[bb+2]; o3 = wd[bb+3];
                } else {
                    const int bb = (15 - dyi) >> 1;        // v_alignbit pattern
                    o0 = (wd[bb]   >> 16) | (wd[bb+1] << 16);
                    o1 = (wd[bb+1] >> 16) | (wd[bb+2] << 16);
                    o2 = (wd[bb+2] >> 16) | (wd[bb+3] << 16);
                    o3 = (wd[bb+3] >> 16) | (wd[bb+4] << 16);
                }
                union { unsigned int u[4]; short8 s; } bq;
                bq.u[0] = o0; bq.u[1] = o1; bq.u[2] = o2; bq.u[3] = o3;
                acc[dyi] = __builtin_amdgcn_mfma_f32_16x16x32_bf16(
                    af0, bq.s, acc[dyi], 0, 0, 0);
            }
        }
    };

    __syncthreads();
    for (int sub = 0; sub < 8; ++sub) {
        if (sub < 7) stageA(sub + 1, (sub + 1) & 1);   // async prefetch under compute
        compute(sub, sub & 1);
        __syncthreads();
    }

    if (PART) {
        // ---- in-block cross-wave reduction via LDS (reuses smem), then plain stores.
        // ALL threads participate in barriers; validity re-derived per item.
        constexpr int NG  = (DYN < 9) ? DYN : 9;          // dyi per phase (36,864B max)
        constexpr int NPH = (DYN + NG - 1) / NG;
        float* red = (float*)smem;                         // [wv][dl][lane][4] floats
        float* pt  = part + TBASE[tgl] + (size_t)(kc * 4 + b) * S;
        const int cpart0 = n0 & 15;
        #pragma unroll
        for (int ph = 0; ph < NPH; ++ph) {
            const int d0 = ph * NG;
            const int nd = (DYN - d0 < NG) ? (DYN - d0) : NG;
            __syncthreads();                               // LDS free for reuse
            #pragma unroll
            for (int dl = 0; dl < NG; ++dl) {
                if (dl >= nd) break;                       // constant after unroll
                *(float4v*)(red + ((wv * NG + dl) * 64 + lane) * 4) = acc[d0 + dl];
            }
            __syncthreads();
            for (int i = tid; i < nd * 64; i += TPB) {
                const int dl = i >> 6;
                const int ln = i & 63;
                const float4v s0 = *(const float4v*)(red + ((0 * NG + dl) * 64 + ln) * 4);
                const float4v s1 = *(const float4v*)(red + ((1 * NG + dl) * 64 + ln) * 4);
                const float4v s2 = *(const float4v*)(red + ((2 * NG + dl) * 64 + ln) * 4);
                const float4v s3 = *(const float4v*)(red + ((3 * NG + dl) * 64 + ln) * 4);
                const float4v s = (s0 + s1) + (s2 + s3);
                const int cc = ln & 15, gg = ln >> 4;
                if ((n0 + cc < 8 * DXN) && (J2 > 0 || cc < 8)) {
                    const int dyi = d0 + dl;
                    #pragma unroll
                    for (int t2 = 0; t2 < 4; ++t2) {
                        const int ml = (gg << 2) + t2;
                        if (ml < vrows)
                            pt[(dyi * MV + moff + ml) * 16 + cpart0 + cc] = s[t2];
                    }
                }
            }
        }
        return;
    }

    if (!validn) return;
    #pragma unroll
    for (int dyi = 0; dyi < DYN; ++dyi) {
        const int dy = dyi - R;
        const int yo = dy < 0 ? dy + 17 : dy;
        #pragma unroll
        for (int t2 = 0; t2 < 4; ++t2) {
            const int ml = (g << 2) + t2;
            if (ml >= vrows) continue;
            const int m = moff + ml;
            const int j1 = m >> 3, ch1 = m & 7;
            const int pb = ((j1 * (9 - j1)) >> 1) + (J2 - j1);
            const int p  = pb * 64 + ((ch1 >> 1) << 4) + ((ch2 >> 1) << 2)
                         + ((ch1 & 1) << 1) + (ch2 & 1);
            atomicAdd(out + (size_t)(p * 4 + b) * 289 + xo * 17 + yo, acc[dyi][t2]);
        }
    }
}

template<bool PRE, bool PART>
__global__ __launch_bounds__(TPB, 3)
void corr_v7(const float* __restrict__ xpsi, const unsigned short* __restrict__ xbf,
             float* __restrict__ out, float* __restrict__ part)
{
    __shared__ __align__(16) unsigned char smem[40704];
    const int bid = blockIdx.x;
    const int t   = bid % NTILE;       // heavy classes first
    const int rem = bid / NTILE;
    const int b   = rem & 3;
    const int kc  = rem >> 2;
    const int n0   = TN0[t];
    const int moff = TMOFF[t];
    const int tgl  = TGL[t];
    if (t < 18)      corr_body<3, PRE, PART>(xpsi, xbf, out, part, smem, tgl, n0, moff, b, kc);
    else if (t < 28) corr_body<2, PRE, PART>(xpsi, xbf, out, part, smem, tgl, n0, moff, b, kc);
    else if (t < 31) corr_body<1, PRE, PART>(xpsi, xbf, out, part, smem, tgl, n0, moff, b, kc);
    else             corr_body<0, PRE, PART>(xpsi, xbf, out, part, smem, tgl, n0, moff, b, kc);
}

// sum the 8 kc partial slices; float4 over 4 consecutive c; out pre-zeroed.
__global__ __launch_bounds__(256)
void reduce2(const float* __restrict__ part, float* __restrict__ out)
{
    const int t  = blockIdx.y;
    const int j2 = (t < 9) ? 3 : (t < 14) ? 2 : (t < 17) ? 1 : 0;
    const int nt = t - ((t < 9) ? 0 : (t < 14) ? 9 : (t < 17) ? 14 : 17);
    const int R = 1 << j2, DXN = 2 * R + 1, DYN = DXN, MV = 8 * (j2 + 1);
    const int S = DYN * MV * 16;
    const int tot = 4 * DYN * MV * 4;            // b * dyi * m * c4
    const int i = blockIdx.x * 256 + threadIdx.x;
    if (i >= tot) return;
    const int c4 = (i & 3) << 2;
    int r2 = i >> 2;
    const int m = r2 % MV;  r2 /= MV;
    const int dyi = r2 % DYN;
    const int b   = r2 / DYN;
    const int ncol0 = nt * 16 + c4;
    if (ncol0 >= 8 * DXN) return;
    const float* q = part + TBASE[t] + (size_t)b * S + (dyi * MV + m) * 16 + c4;
    float4 v = {0.f, 0.f, 0.f, 0.f};
    #pragma unroll
    for (int qq = 0; qq < 8; ++qq) {
        const float4 w = *(const float4*)(q + (size_t)qq * 4 * S);
        v.x += w.x; v.y += w.y; v.z += w.z; v.w += w.w;
    }
    const int dy = dyi - R;
    const int yo = dy < 0 ? dy + 17 : dy;
    const int j1 = m >> 3, ch1 = m & 7;
    const int pb = ((j1 * (9 - j1)) >> 1) + (j2 - j1);
    const float vv[4] = {v.x, v.y, v.z, v.w};
    #pragma unroll
    for (int e = 0; e < 4; ++e) {
        const int ncol = ncol0 + e;
        if (ncol >= 8 * DXN) break;
        const int ch2 = ncol / DXN;
        const int dxi = ncol - ch2 * DXN;
        const int dx  = dxi - R;
        const int xo  = dx < 0 ? dx + 17 : dx;
        const int p   = pb * 64 + ((ch1 >> 1) << 4) + ((ch2 >> 1) << 2)
                      + ((ch1 & 1) << 1) + (ch2 & 1);
        out[(size_t)(p * 4 + b) * 289 + xo * 17 + yo] = vv[e];
    }
}

extern "C" void kernel_launch(void* const* d_in, const int* in_sizes, int n_in,
                              void* d_out, int out_size, void* d_ws, size_t ws_size,
                              hipStream_t stream) {
    const float* xpsi = (const float*)d_in[0];
    float* out = (float*)d_out;

    if (ws_size >= (size_t)PBYTE + (size_t)NPART * 4) {
        unsigned short* xbf = (unsigned short*)d_ws;
        float* part = (float*)((char*)d_ws + PBYTE);
        hipMemsetAsync(d_out, 0, (size_t)out_size * sizeof(float), stream);
        conv_bf16<<<(NGR + ZPG + 255) / 256, 256, 0, stream>>>(xpsi, xbf);
        corr_v7<true, true><<<NTILE * 32, TPB, 0, stream>>>(xpsi, xbf, out, part);
        reduce2<<<dim3(34, 19), 256, 0, stream>>>(part, out);
    } else if (ws_size >= (size_t)PBYTE) {
        unsigned short* xbf = (unsigned short*)d_ws;
        hipMemsetAsync(d_out, 0, (size_t)out_size * sizeof(float), stream);
        conv_bf16<<<(NGR + ZPG + 255) / 256, 256, 0, stream>>>(xpsi, xbf);
        corr_v7<true, false><<<NTILE * 32, TPB, 0, stream>>>(xpsi, xbf, out, nullptr);
    } else {
        hipMemsetAsync(d_out, 0, (size_t)out_size * sizeof(float), stream);
        corr_v7<false, false><<<NTILE * 32, TPB, 0, stream>>>(xpsi, nullptr, out, nullptr);
    }
}

// Round 8
// 46.232 us; speedup vs baseline: 9.1711x; 1.0173x over previous
//
#include <hip/hip_runtime.h>

typedef __attribute__((ext_vector_type(8))) short short8;
typedef __attribute__((ext_vector_type(4))) float float4v;
typedef __attribute__((address_space(1))) const unsigned int gu32;
typedef __attribute__((address_space(3))) unsigned int lu32;

#define TPB 256
#define NXPSI (4*4*8*16384)      /* 2097152 fp32 elements */
#define NGR   (NXPSI/4)          /* 524288 float4 granules */
#define ZPG   64                 /* zero-page ushort4 granules -> 512B */
#define PBYTE (NXPSI*2 + ZPG*8)  /* partial region byte offset = 4194816 */
#define NPART 3207168            /* partial floats: 8 kc-slices (in-block wv-reduced) */
#define NOUT  739840             /* 640*4*289 */

// per-partial-tile base (floats), 19 tiles. size(t) = 8*4*DYN*MV*16
__device__ __constant__ int TBASE[19] = {
    0, 278528, 557056, 835584, 1114112, 1392640, 1671168, 1949696, 2228224,
    2506752, 2617344, 2727936, 2838528, 2949120,
    3059712, 3100672, 3141632,
    3182592, 3194880};

static __device__ __forceinline__ unsigned short f2bf(float f) {
    unsigned int u = __builtin_bit_cast(unsigned int, f);
    u = (u + 0x7FFFu + ((u >> 16) & 1u)) >> 16;     // RNE, data has no NaN
    return (unsigned short)u;
}

__global__ __launch_bounds__(256)
void conv_bf16(const float* __restrict__ in, unsigned short* __restrict__ outw) {
    const int g = blockIdx.x * 256 + threadIdx.x;
    if (g < NGR) {
        const float4 v = reinterpret_cast<const float4*>(in)[g];
        reinterpret_cast<ushort4*>(outw)[g] =
            ushort4{f2bf(v.x), f2bf(v.y), f2bf(v.z), f2bf(v.w)};
    } else if (g < NGR + ZPG) {
        reinterpret_cast<ushort4*>(outw)[g] = ushort4{0, 0, 0, 0};
    }
}

// corr[p,b,dx,dy] = sum_{u,v} a[u,v]*b[(u-dx)%128,(v-dy)%128]; nonzero |dx|,|dy|<=r=2^j2.
// Waves split K (wave wv owns K-slices wv, wv+4); cross-wave sum via LDS before store.
template<int J2, bool PRE, bool PART>
static __device__ __forceinline__ void corr_body(
        const float* __restrict__ xpsi, const unsigned short* __restrict__ xbf,
        float* __restrict__ out, float* __restrict__ part,
        unsigned char* smem, int tgl, int n0, int moff, int b, int kc)
{
    constexpr int R    = 1 << J2;
    constexpr int DXN  = 2 * R + 1;
    constexpr int DYN  = DXN;
    constexpr int MV   = 8 * (J2 + 1);            // class m-rows (partial layout)
    constexpr int ROWS = 16 + 2 * R;              // B row window
    constexpr int ABUF = 16 * 256;                // elements per A buffer (16 rows x 2 K-rows)
    constexpr int S    = DYN * MV * 16;           // floats per partial slice
    constexpr int W    = (J2 == 0) ? 8 : 16;      // n-tile width

    unsigned short* a_lds = (unsigned short*)smem;               // 2 x ABUF el
    unsigned short* b_lds = (unsigned short*)(smem + 4 * ABUF);  // byte offset 16384

    const int k0    = kc * 16;
    const int vrows = (MV - moff < 16) ? MV - moff : 16;         // valid staged rows

    const int ch2lo = n0 / DXN;
    int nhi = n0 + W - 1; if (nhi > 8 * DXN - 1) nhi = 8 * DXN - 1;
    const int nimg = nhi / DXN - ch2lo + 1;

    const int tid  = threadIdx.x;
    const int lane = tid & 63;
    const int wv   = tid >> 6;
    const int c    = lane & 15;       // N-col in tile / A m-row
    const int g    = lane >> 4;       // K-group

    const int ncol    = n0 + c;
    const bool validn = (ncol < 8 * DXN) && (J2 > 0 || c < 8);
    const int ncc     = validn ? ncol : n0;
    const int ch2     = ncc / DXN;
    const int dxi     = ncc - ch2 * DXN;
    const int dx      = dxi - R;
    const int xo      = dx < 0 ? dx + 17 : dx;
    const int bst     = ((ch2 - ch2lo) * ROWS + (2 * R - dxi)) * 152;

    // ---- A stage: 16 rows x [2 K-rows x 128px], granule swizzle lo=(o&31)^(ms&15) ----
    auto stageA = [&](int sub, int bufi) {
        unsigned short* ab = a_lds + bufi * ABUF;
        #pragma unroll
        for (int it = 0; it < 2; ++it) {          // 512 granules / 256 threads
            const int o  = it * TPB + tid;
            const int ms = o >> 5;
            const int lo = (o & 31) ^ ms;
            const int me = moff + ms;
            const int j1 = me >> 3, ch1 = me & 7;
            if (PRE) {
                const unsigned short* src = (ms < vrows)
                    ? xbf + ((((size_t)j1*4 + b)*8) + ch1) * 16384
                          + (k0 + sub * 2 + (lo >> 4)) * 128 + ((lo & 15) << 3)
                    : xbf + NXPSI + ((lo & 31) << 3);          // zero page
                __builtin_amdgcn_global_load_lds((gu32*)src, (lu32*)(ab + o * 8), 16, 0, 0);
            } else {
                ushort4 w0{0,0,0,0}, w1{0,0,0,0};
                if (ms < vrows) {
                    const float* s = xpsi + ((((size_t)j1*4 + b)*8) + ch1) * 16384
                                   + (k0 + sub * 2 + (lo >> 4)) * 128 + ((lo & 15) << 3);
                    const float4 f0 = ((const float4*)s)[0];
                    const float4 f1 = ((const float4*)s)[1];
                    w0 = ushort4{f2bf(f0.x), f2bf(f0.y), f2bf(f0.z), f2bf(f0.w)};
                    w1 = ushort4{f2bf(f1.x), f2bf(f1.y), f2bf(f1.z), f2bf(f1.w)};
                }
                *(ushort4*)(ab + o * 8)     = w0;
                *(ushort4*)(ab + o * 8 + 4) = w1;
            }
        }
    };

    // issue first A-chunk (async) before B staging so it flies underneath
    stageA(0, 0);

    // ---- stage B once: [nimg][ROWS][144 +8pad], col tc <-> src (tc+R-16)&127 ----
    if (PRE && J2 >= 2) {
        // wrap boundary 4-aligned for R in {4,8} -> clean ushort4 granules
        for (int ci = 0; ci < nimg; ++ci) {
            const unsigned short* img = xbf + ((((size_t)J2*4 + b)*8) + ch2lo + ci) * 16384;
            const int ng2 = ROWS * 36;
            for (int i = tid; i < ng2; i += TPB) {
                const int tr = i / 36, tc = (i - tr * 36) * 4;
                const int sr = (k0 - R + tr) & 127;
                const int sc = (tc + R - 16) & 127;
                *(ushort4*)(b_lds + (ci * ROWS + tr) * 152 + tc) =
                    *(const ushort4*)(img + sr * 128 + sc);
            }
        }
    } else {
        const int tot = nimg * ROWS * 144;
        for (int i = tid; i < tot; i += TPB) {
            const int ci = i / (ROWS * 144);
            const int rr = i - ci * (ROWS * 144);
            const int tr = rr / 144, tc = rr - tr * 144;
            const int sr = (k0 - R + tr) & 127;
            const int sc = (tc + R - 16) & 127;
            b_lds[(ci * ROWS + tr) * 152 + tc] = PRE
                ? xbf[((((size_t)J2*4 + b)*8) + ch2lo + ci) * 16384 + sr * 128 + sc]
                : f2bf(xpsi[((((size_t)J2*4 + b)*8) + ch2lo + ci) * 16384 + sr * 128 + sc]);
        }
    }

    float4v acc[DYN];
    #pragma unroll
    for (int i = 0; i < DYN; ++i) acc[i] = (float4v)0.f;

    auto compute = [&](int sub, int bufi) {
        const char* abase = (const char*)(a_lds + bufi * ABUF);
        #pragma unroll
        for (int i2 = 0; i2 < 2; ++i2) {          // K-slice = wv + 4*i2
            const int loff = (((i2 << 8) | (wv << 6) | (g << 4))) ^ (c << 4);
            const short8 af0 = *(const short8*)(abase + c * 512 + loff);

            const unsigned short* bp = b_lds + bst + (sub * 2 + i2) * 152
                                     + (wv << 5) + (g << 3);
            const uint4 wA = *(const uint4*)bp;
            const uint4 wB = *(const uint4*)(bp + 8);
            const uint4 wC = *(const uint4*)(bp + 16);
            const unsigned int wd[12] = {wA.x,wA.y,wA.z,wA.w, wB.x,wB.y,wB.z,wB.w,
                                         wC.x,wC.y,wC.z,wC.w};
            __builtin_amdgcn_s_setprio(1);
            #pragma unroll
            for (int dyi = 0; dyi < DYN; ++dyi) {
                unsigned int o0, o1, o2, o3;
                if ((dyi & 1) == 0) {
                    const int bb = 8 - (dyi >> 1);
                    o0 = wd[bb]; o1 = wd[bb+1]; o2 = wd[bb+2]; o3 = wd[bb+3];
                } else {
                    const int bb = (15 - dyi) >> 1;        // v_alignbit pattern
                    o0 = (wd[bb]   >> 16) | (wd[bb+1] << 16);
                    o1 = (wd[bb+1] >> 16) | (wd[bb+2] << 16);
                    o2 = (wd[bb+2] >> 16) | (wd[bb+3] << 16);
                    o3 = (wd[bb+3] >> 16) | (wd[bb+4] << 16);
                }
                union { unsigned int u[4]; short8 s; } bq;
                bq.u[0] = o0; bq.u[1] = o1; bq.u[2] = o2; bq.u[3] = o3;
                acc[dyi] = __builtin_amdgcn_mfma_f32_16x16x32_bf16(
                    af0, bq.s, acc[dyi], 0, 0, 0);
            }
            __builtin_amdgcn_s_setprio(0);
        }
    };

    __syncthreads();
    for (int sub = 0; sub < 8; ++sub) {
        if (sub < 7) stageA(sub + 1, (sub + 1) & 1);   // async prefetch under compute
        compute(sub, sub & 1);
        __syncthreads();
    }

    if (PART) {
        // ---- in-block cross-wave reduction via LDS (reuses smem), then plain stores.
        // ALL threads participate in barriers; validity re-derived per item.
        constexpr int NG  = (DYN < 9) ? DYN : 9;          // dyi per phase (36,864B max)
        constexpr int NPH = (DYN + NG - 1) / NG;
        float* red = (float*)smem;                         // [wv][dl][lane][4] floats
        float* pt  = part + TBASE[tgl] + (size_t)(kc * 4 + b) * S;
        const int cpart0 = n0 & 15;
        #pragma unroll
        for (int ph = 0; ph < NPH; ++ph) {
            const int d0 = ph * NG;
            const int nd = (DYN - d0 < NG) ? (DYN - d0) : NG;
            __syncthreads();                               // LDS free for reuse
            #pragma unroll
            for (int dl = 0; dl < NG; ++dl) {
                if (dl >= nd) break;                       // constant after unroll
                *(float4v*)(red + ((wv * NG + dl) * 64 + lane) * 4) = acc[d0 + dl];
            }
            __syncthreads();
            for (int i = tid; i < nd * 64; i += TPB) {
                const int dl = i >> 6;
                const int ln = i & 63;
                const float4v s0 = *(const float4v*)(red + ((0 * NG + dl) * 64 + ln) * 4);
                const float4v s1 = *(const float4v*)(red + ((1 * NG + dl) * 64 + ln) * 4);
                const float4v s2 = *(const float4v*)(red + ((2 * NG + dl) * 64 + ln) * 4);
                const float4v s3 = *(const float4v*)(red + ((3 * NG + dl) * 64 + ln) * 4);
                const float4v s = (s0 + s1) + (s2 + s3);
                const int cc = ln & 15, gg = ln >> 4;
                if ((n0 + cc < 8 * DXN) && (J2 > 0 || cc < 8)) {
                    const int dyi = d0 + dl;
                    #pragma unroll
                    for (int t2 = 0; t2 < 4; ++t2) {
                        const int ml = (gg << 2) + t2;
                        if (ml < vrows)
                            pt[(dyi * MV + moff + ml) * 16 + cpart0 + cc] = s[t2];
                    }
                }
            }
        }
        return;
    }

    if (!validn) return;
    #pragma unroll
    for (int dyi = 0; dyi < DYN; ++dyi) {
        const int dy = dyi - R;
        const int yo = dy < 0 ? dy + 17 : dy;
        #pragma unroll
        for (int t2 = 0; t2 < 4; ++t2) {
            const int ml = (g << 2) + t2;
            if (ml >= vrows) continue;
            const int m = moff + ml;
            const int j1 = m >> 3, ch1 = m & 7;
            const int pb = ((j1 * (9 - j1)) >> 1) + (J2 - j1);
            const int p  = pb * 64 + ((ch1 >> 1) << 4) + ((ch2 >> 1) << 2)
                         + ((ch1 & 1) << 1) + (ch2 & 1);
            atomicAdd(out + (size_t)(p * 4 + b) * 289 + xo * 17 + yo, acc[dyi][t2]);
        }
    }
}

// XCD-affine mapping: group = bid&7 -> (b, m-half) pinned to one XCD (bids
// round-robin over XCDs). Within a group, kc-major order so the n-tiles that
// share an A-chunk run adjacently on the same XCD's L2 (1 miss + N-1 hits).
// Per group: 17 tile-slots x 8 kc = 136 blocks = 4.25 blocks/CU on its XCD.
// mh=0 groups carry J2=1 slots, mh=1 carry J2=0 -> balanced halves.
template<bool PRE, bool PART>
__global__ __launch_bounds__(TPB, 3)
void corr_v8(const float* __restrict__ xpsi, const unsigned short* __restrict__ xbf,
             float* __restrict__ out, float* __restrict__ part)
{
    __shared__ __align__(16) unsigned char smem[40704];
    const int bid = blockIdx.x;
    const int g8  = bid & 7;
    const int b   = g8 >> 1;
    const int mh  = g8 & 1;
    const int w   = bid >> 3;
    const int kc  = w / 17;
    const int s   = w - kc * 17;
    if (s < 9)
        corr_body<3, PRE, PART>(xpsi, xbf, out, part, smem, s, 16 * s, 16 * mh, b, kc);
    else if (s < 14)
        corr_body<2, PRE, PART>(xpsi, xbf, out, part, smem, s, 16 * (s - 9), 16 * mh, b, kc);
    else if (mh == 0)
        corr_body<1, PRE, PART>(xpsi, xbf, out, part, smem, s, 16 * (s - 14), 0, b, kc);
    else
        corr_body<0, PRE, PART>(xpsi, xbf, out, part, smem,
                                (s < 16) ? 17 : 18, 8 * (s - 14), 0, b, kc);
}

// sum the 8 kc partial slices; float4 over 4 consecutive c; out pre-zeroed.
__global__ __launch_bounds__(256)
void reduce2(const float* __restrict__ part, float* __restrict__ out)
{
    const int t  = blockIdx.y;
    const int j2 = (t < 9) ? 3 : (t < 14) ? 2 : (t < 17) ? 1 : 0;
    const int nt = t - ((t < 9) ? 0 : (t < 14) ? 9 : (t < 17) ? 14 : 17);
    const int R = 1 << j2, DXN = 2 * R + 1, DYN = DXN, MV = 8 * (j2 + 1);
    const int S = DYN * MV * 16;
    const int tot = 4 * DYN * MV * 4;            // b * dyi * m * c4
    const int i = blockIdx.x * 256 + threadIdx.x;
    if (i >= tot) return;
    const int c4 = (i & 3) << 2;
    int r2 = i >> 2;
    const int m = r2 % MV;  r2 /= MV;
    const int dyi = r2 % DYN;
    const int b   = r2 / DYN;
    const int ncol0 = nt * 16 + c4;
    if (ncol0 >= 8 * DXN) return;
    const float* q = part + TBASE[t] + (size_t)b * S + (dyi * MV + m) * 16 + c4;
    float4 v = {0.f, 0.f, 0.f, 0.f};
    #pragma unroll
    for (int qq = 0; qq < 8; ++qq) {
        const float4 w = *(const float4*)(q + (size_t)qq * 4 * S);
        v.x += w.x; v.y += w.y; v.z += w.z; v.w += w.w;
    }
    const int dy = dyi - R;
    const int yo = dy < 0 ? dy + 17 : dy;
    const int j1 = m >> 3, ch1 = m & 7;
    const int pb = ((j1 * (9 - j1)) >> 1) + (j2 - j1);
    const float vv[4] = {v.x, v.y, v.z, v.w};
    #pragma unroll
    for (int e = 0; e < 4; ++e) {
        const int ncol = ncol0 + e;
        if (ncol >= 8 * DXN) break;
        const int ch2 = ncol / DXN;
        const int dxi = ncol - ch2 * DXN;
        const int dx  = dxi - R;
        const int xo  = dx < 0 ? dx + 17 : dx;
        const int p   = pb * 64 + ((ch1 >> 1) << 4) + ((ch2 >> 1) << 2)
                      + ((ch1 & 1) << 1) + (ch2 & 1);
        out[(size_t)(p * 4 + b) * 289 + xo * 17 + yo] = vv[e];
    }
}

extern "C" void kernel_launch(void* const* d_in, const int* in_sizes, int n_in,
                              void* d_out, int out_size, void* d_ws, size_t ws_size,
                              hipStream_t stream) {
    const float* xpsi = (const float*)d_in[0];
    float* out = (float*)d_out;

    if (ws_size >= (size_t)PBYTE + (size_t)NPART * 4) {
        unsigned short* xbf = (unsigned short*)d_ws;
        float* part = (float*)((char*)d_ws + PBYTE);
        hipMemsetAsync(d_out, 0, (size_t)out_size * sizeof(float), stream);
        conv_bf16<<<(NGR + ZPG + 255) / 256, 256, 0, stream>>>(xpsi, xbf);
        corr_v8<true, true><<<1088, TPB, 0, stream>>>(xpsi, xbf, out, part);
        reduce2<<<dim3(34, 19), 256, 0, stream>>>(part, out);
    } else if (ws_size >= (size_t)PBYTE) {
        unsigned short* xbf = (unsigned short*)d_ws;
        hipMemsetAsync(d_out, 0, (size_t)out_size * sizeof(float), stream);
        conv_bf16<<<(NGR + ZPG + 255) / 256, 256, 0, stream>>>(xpsi, xbf);
        corr_v8<true, false><<<1088, TPB, 0, stream>>>(xpsi, xbf, out, nullptr);
    } else {
        hipMemsetAsync(d_out, 0, (size_t)out_size * sizeof(float), stream);
        corr_v8<false, false><<<1088, TPB, 0, stream>>>(xpsi, nullptr, out, nullptr);
    }
}

// Round 9
// 45.350 us; speedup vs baseline: 9.3494x; 1.0194x over previous
//
#include <hip/hip_runtime.h>

typedef __attribute__((ext_vector_type(8))) short short8;
typedef __attribute__((ext_vector_type(4))) float float4v;

#define TPB 256
#define NPART 3207168            /* partial floats: 8 kc-slices (in-block wv-reduced) */
#define NOUT  739840             /* 640*4*289 */

// per-partial-tile base (floats), 19 tiles. size(t) = 8*4*DYN*MV*16
__device__ __constant__ int TBASE[19] = {
    0, 278528, 557056, 835584, 1114112, 1392640, 1671168, 1949696, 2228224,
    2506752, 2617344, 2727936, 2838528, 2949120,
    3059712, 3100672, 3141632,
    3182592, 3194880};
__device__ __constant__ unsigned char J1T[10] = {0,0,0,0,1,1,1,2,2,3};
__device__ __constant__ unsigned char J2T[10] = {0,1,2,3,1,2,3,2,3,3};
__device__ __constant__ unsigned char TSTART[4] = {17,14,9,0};   // class->first tile

static __device__ __forceinline__ unsigned short f2bf(float f) {
    unsigned int u = __builtin_bit_cast(unsigned int, f);
    u = (u + 0x7FFFu + ((u >> 16) & 1u)) >> 16;     // RNE, data has no NaN
    return (unsigned short)u;
}

// corr[p,b,dx,dy] = sum_{u,v} a[u,v]*b[(u-dx)%128,(v-dy)%128]; nonzero |dx|,|dy|<=r=2^j2.
// Waves split K (wave wv owns K-slices wv, wv+4); cross-wave sum via LDS before store.
// Stages fp32 -> bf16 in-kernel (no pre-convert pass); A loads reg-staged early (T14).
template<int J2, bool PART>
static __device__ __forceinline__ void corr_body(
        const float* __restrict__ xpsi,
        float* __restrict__ out, float* __restrict__ part,
        unsigned char* smem, int tgl, int n0, int moff, int b, int kc)
{
    constexpr int R    = 1 << J2;
    constexpr int DXN  = 2 * R + 1;
    constexpr int DYN  = DXN;
    constexpr int MV   = 8 * (J2 + 1);            // class m-rows (partial layout)
    constexpr int ROWS = 16 + 2 * R;              // B row window
    constexpr int ABUF = 16 * 256;                // elements per A buffer (16 rows x 2 K-rows)
    constexpr int S    = DYN * MV * 16;           // floats per partial slice
    constexpr int W    = (J2 == 0) ? 8 : 16;      // n-tile width

    unsigned short* a_lds = (unsigned short*)smem;               // 2 x ABUF el
    unsigned short* b_lds = (unsigned short*)(smem + 4 * ABUF);  // byte offset 16384

    const int k0    = kc * 16;
    const int vrows = (MV - moff < 16) ? MV - moff : 16;         // valid staged rows

    const int ch2lo = n0 / DXN;
    int nhi = n0 + W - 1; if (nhi > 8 * DXN - 1) nhi = 8 * DXN - 1;
    const int nimg = nhi / DXN - ch2lo + 1;

    const int tid  = threadIdx.x;
    const int lane = tid & 63;
    const int wv   = tid >> 6;
    const int c    = lane & 15;       // N-col in tile / A m-row
    const int g    = lane >> 4;       // K-group

    const int ncol    = n0 + c;
    const bool validn = (ncol < 8 * DXN) && (J2 > 0 || c < 8);
    const int ncc     = validn ? ncol : n0;
    const int ch2     = ncc / DXN;
    const int dxi     = ncc - ch2 * DXN;
    const int dx      = dxi - R;
    const int xo      = dx < 0 ? dx + 17 : dx;
    const int bst     = ((ch2 - ch2lo) * ROWS + (2 * R - dxi)) * 152;

    // ---- A stage, split load/write (T14): loads fly under compute ----
    // layout per buffer: 16 rows x [2 K-rows x 128px], granule swizzle lo=(o&31)^ms
    float4 ar[4];                                  // 2 granules x 2 float4 in flight
    auto loadA = [&](int sub) {
        #pragma unroll
        for (int it = 0; it < 2; ++it) {
            const int o  = it * TPB + tid;
            const int ms = o >> 5;
            const int lo = (o & 31) ^ ms;
            const int me = moff + ms;
            const int j1 = me >> 3, ch1 = me & 7;
            if (ms < vrows) {
                const float* s = xpsi + ((((size_t)j1*4 + b)*8) + ch1) * 16384
                               + (k0 + sub * 2 + (lo >> 4)) * 128 + ((lo & 15) << 3);
                ar[2*it]   = ((const float4*)s)[0];
                ar[2*it+1] = ((const float4*)s)[1];
            } else {
                ar[2*it]   = float4{0.f,0.f,0.f,0.f};
                ar[2*it+1] = float4{0.f,0.f,0.f,0.f};
            }
        }
    };
    auto writeA = [&](int bufi) {
        unsigned short* ab = a_lds + bufi * ABUF;
        #pragma unroll
        for (int it = 0; it < 2; ++it) {
            const int o = it * TPB + tid;
            const float4 f0 = ar[2*it], f1 = ar[2*it+1];
            *(ushort4*)(ab + o * 8)     = ushort4{f2bf(f0.x),f2bf(f0.y),f2bf(f0.z),f2bf(f0.w)};
            *(ushort4*)(ab + o * 8 + 4) = ushort4{f2bf(f1.x),f2bf(f1.y),f2bf(f1.z),f2bf(f1.w)};
        }
    };

    loadA(0);                                      // issue first A loads

    // ---- stage B once: [nimg][ROWS][144 +8pad], col tc <-> src (tc+R-16)&127 ----
    if (J2 >= 2) {
        // wrap boundary 4-aligned for R in {4,8} -> clean float4 granules
        for (int ci = 0; ci < nimg; ++ci) {
            const float* img = xpsi + ((((size_t)J2*4 + b)*8) + ch2lo + ci) * 16384;
            const int ng2 = ROWS * 36;
            for (int i = tid; i < ng2; i += TPB) {
                const int tr = i / 36, tc = (i - tr * 36) * 4;
                const int sr = (k0 - R + tr) & 127;
                const int sc = (tc + R - 16) & 127;
                const float4 v = *(const float4*)(img + sr * 128 + sc);
                *(ushort4*)(b_lds + (ci * ROWS + tr) * 152 + tc) =
                    ushort4{f2bf(v.x), f2bf(v.y), f2bf(v.z), f2bf(v.w)};
            }
        }
    } else {
        const int tot = nimg * ROWS * 144;
        for (int i = tid; i < tot; i += TPB) {
            const int ci = i / (ROWS * 144);
            const int rr = i - ci * (ROWS * 144);
            const int tr = rr / 144, tc = rr - tr * 144;
            const int sr = (k0 - R + tr) & 127;
            const int sc = (tc + R - 16) & 127;
            b_lds[(ci * ROWS + tr) * 152 + tc] =
                f2bf(xpsi[((((size_t)J2*4 + b)*8) + ch2lo + ci) * 16384 + sr * 128 + sc]);
        }
    }

    writeA(0);                                     // vmcnt-wait lands here, after B issue

    float4v acc[DYN];
    #pragma unroll
    for (int i = 0; i < DYN; ++i) acc[i] = (float4v)0.f;

    auto compute = [&](int sub, int bufi) {
        const char* abase = (const char*)(a_lds + bufi * ABUF);
        #pragma unroll
        for (int i2 = 0; i2 < 2; ++i2) {          // K-slice = wv + 4*i2
            const int loff = (((i2 << 8) | (wv << 6) | (g << 4))) ^ (c << 4);
            const short8 af0 = *(const short8*)(abase + c * 512 + loff);

            const unsigned short* bp = b_lds + bst + (sub * 2 + i2) * 152
                                     + (wv << 5) + (g << 3);
            const uint4 wA = *(const uint4*)bp;
            const uint4 wB = *(const uint4*)(bp + 8);
            const uint4 wC = *(const uint4*)(bp + 16);
            const unsigned int wd[12] = {wA.x,wA.y,wA.z,wA.w, wB.x,wB.y,wB.z,wB.w,
                                         wC.x,wC.y,wC.z,wC.w};
            #pragma unroll
            for (int dyi = 0; dyi < DYN; ++dyi) {
                unsigned int o0, o1, o2, o3;
                if ((dyi & 1) == 0) {
                    const int bb = 8 - (dyi >> 1);
                    o0 = wd[bb]; o1 = wd[bb+1]; o2 = wd[bb+2]; o3 = wd[bb+3];
                } else {
                    const int bb = (15 - dyi) >> 1;        // v_alignbit pattern
                    o0 = (wd[bb]   >> 16) | (wd[bb+1] << 16);
                    o1 = (wd[bb+1] >> 16) | (wd[bb+2] << 16);
                    o2 = (wd[bb+2] >> 16) | (wd[bb+3] << 16);
                    o3 = (wd[bb+3] >> 16) | (wd[bb+4] << 16);
                }
                union { unsigned int u[4]; short8 s; } bq;
                bq.u[0] = o0; bq.u[1] = o1; bq.u[2] = o2; bq.u[3] = o3;
                acc[dyi] = __builtin_amdgcn_mfma_f32_16x16x32_bf16(
                    af0, bq.s, acc[dyi], 0, 0, 0);
            }
        }
    };

    __syncthreads();
    for (int sub = 0; sub < 8; ++sub) {
        if (sub < 7) loadA(sub + 1);               // issue next loads (regs)
        compute(sub, sub & 1);
        if (sub < 7) writeA((sub + 1) & 1);        // convert+write after compute
        __syncthreads();
    }

    if (PART) {
        // ---- in-block cross-wave reduction via LDS (reuses smem), then plain stores.
        // ALL threads participate in barriers; validity re-derived per item.
        constexpr int NG  = (DYN < 9) ? DYN : 9;          // dyi per phase (36,864B max)
        constexpr int NPH = (DYN + NG - 1) / NG;
        float* red = (float*)smem;                         // [wv][dl][lane][4] floats
        float* pt  = part + TBASE[tgl] + (size_t)(kc * 4 + b) * S;
        const int cpart0 = n0 & 15;
        #pragma unroll
        for (int ph = 0; ph < NPH; ++ph) {
            const int d0 = ph * NG;
            const int nd = (DYN - d0 < NG) ? (DYN - d0) : NG;
            __syncthreads();                               // LDS free for reuse
            #pragma unroll
            for (int dl = 0; dl < NG; ++dl) {
                if (dl >= nd) break;                       // constant after unroll
                *(float4v*)(red + ((wv * NG + dl) * 64 + lane) * 4) = acc[d0 + dl];
            }
            __syncthreads();
            for (int i = tid; i < nd * 64; i += TPB) {
                const int dl = i >> 6;
                const int ln = i & 63;
                const float4v s0 = *(const float4v*)(red + ((0 * NG + dl) * 64 + ln) * 4);
                const float4v s1 = *(const float4v*)(red + ((1 * NG + dl) * 64 + ln) * 4);
                const float4v s2 = *(const float4v*)(red + ((2 * NG + dl) * 64 + ln) * 4);
                const float4v s3 = *(const float4v*)(red + ((3 * NG + dl) * 64 + ln) * 4);
                const float4v s = (s0 + s1) + (s2 + s3);
                const int cc = ln & 15, gg = ln >> 4;
                if ((n0 + cc < 8 * DXN) && (J2 > 0 || cc < 8)) {
                    const int dyi = d0 + dl;
                    #pragma unroll
                    for (int t2 = 0; t2 < 4; ++t2) {
                        const int ml = (gg << 2) + t2;
                        if (ml < vrows)
                            pt[(dyi * MV + moff + ml) * 16 + cpart0 + cc] = s[t2];
                    }
                }
            }
        }
        return;
    }

    if (!validn) return;
    #pragma unroll
    for (int dyi = 0; dyi < DYN; ++dyi) {
        const int dy = dyi - R;
        const int yo = dy < 0 ? dy + 17 : dy;
        #pragma unroll
        for (int t2 = 0; t2 < 4; ++t2) {
            const int ml = (g << 2) + t2;
            if (ml >= vrows) continue;
            const int m = moff + ml;
            const int j1 = m >> 3, ch1 = m & 7;
            const int pb = ((j1 * (9 - j1)) >> 1) + (J2 - j1);
            const int p  = pb * 64 + ((ch1 >> 1) << 4) + ((ch2 >> 1) << 2)
                         + ((ch1 & 1) << 1) + (ch2 & 1);
            atomicAdd(out + (size_t)(p * 4 + b) * 289 + xo * 17 + yo, acc[dyi][t2]);
        }
    }
}

// group = bid&7 -> (b, m-half); within a group, kc-major so n-tiles sharing an
// A-chunk run temporally adjacent (L2/L3 reuse). 17 tile-slots x 8 kc x 8 groups.
template<bool PART>
__global__ __launch_bounds__(TPB, 3)
void corr_v9(const float* __restrict__ xpsi,
             float* __restrict__ out, float* __restrict__ part)
{
    __shared__ __align__(16) unsigned char smem[40704];
    const int bid = blockIdx.x;
    const int g8  = bid & 7;
    const int b   = g8 >> 1;
    const int mh  = g8 & 1;
    const int w   = bid >> 3;
    const int kc  = w / 17;
    const int s   = w - kc * 17;
    if (s < 9)
        corr_body<3, PART>(xpsi, out, part, smem, s, 16 * s, 16 * mh, b, kc);
    else if (s < 14)
        corr_body<2, PART>(xpsi, out, part, smem, s, 16 * (s - 9), 16 * mh, b, kc);
    else if (mh == 0)
        corr_body<1, PART>(xpsi, out, part, smem, s, 16 * (s - 14), 0, b, kc);
    else
        corr_body<0, PART>(xpsi, out, part, smem,
                           (s < 16) ? 17 : 18, 8 * (s - 14), 0, b, kc);
}

// Full-range reduce: one thread per output element; sums the 8 kc partial
// slices inside the mask, writes zeros outside -> no memset dispatch needed.
__global__ __launch_bounds__(256)
void reduce_k(const float* __restrict__ part, float* __restrict__ out)
{
    const int o = blockIdx.x * 256 + threadIdx.x;
    if (o >= NOUT) return;
    const int p  = o / 1156;            // 4*289
    const int r1 = o - p * 1156;
    const int b  = r1 / 289;
    const int s  = r1 - b * 289;
    const int xo = s / 17, yo = s - xo * 17;
    const int pb = p >> 6, cc = p & 63;
    const int j1 = J1T[pb], j2 = J2T[pb];
    const int R  = 1 << j2;
    const int dx = xo <= 8 ? xo : xo - 17;
    const int dy = yo <= 8 ? yo : yo - 17;
    float v = 0.f;
    if (dx >= -R && dx <= R && dy >= -R && dy <= R) {
        const int ch1 = ((cc >> 4) & 3) * 2 + ((cc >> 1) & 1);
        const int ch2 = ((cc >> 2) & 3) * 2 + (cc & 1);
        const int DYN = 2 * R + 1, MV = 8 * (j2 + 1);
        const int ncol = ch2 * DYN + (dx + R);
        const int t = TSTART[j2] + (ncol >> 4);
        const int c = ncol & 15;
        const int m = j1 * 8 + ch1;
        const int S = DYN * MV * 16;
        const float* q = part + TBASE[t]
                       + ((size_t)(b * DYN + (dy + R)) * MV + m) * 16 + c;
        #pragma unroll
        for (int kc = 0; kc < 8; ++kc) v += q[(size_t)kc * 4 * S];
    }
    out[o] = v;
}

extern "C" void kernel_launch(void* const* d_in, const int* in_sizes, int n_in,
                              void* d_out, int out_size, void* d_ws, size_t ws_size,
                              hipStream_t stream) {
    const float* xpsi = (const float*)d_in[0];
    float* out = (float*)d_out;

    if (ws_size >= (size_t)NPART * 4) {
        float* part = (float*)d_ws;
        corr_v9<true><<<1088, TPB, 0, stream>>>(xpsi, out, part);
        reduce_k<<<(NOUT + 255) / 256, 256, 0, stream>>>(part, out);
    } else {
        hipMemsetAsync(d_out, 0, (size_t)out_size * sizeof(float), stream);
        corr_v9<false><<<1088, TPB, 0, stream>>>(xpsi, out, nullptr);
    }
}